// Round 10
// baseline (848.890 us; speedup 1.0000x reference)
//
#include <hip/hip_runtime.h>
#include <hip/hip_bf16.h>
#include <math.h>

#define NL   6
#define HD   512
#define NHD  8
#define DK   64
#define DFFN 1024
#define NB   8
#define TT   512
#define MROWS (NB*TT)   // 4096
#define SQC  262144     // 512*512

typedef __hip_bfloat16 bf16;
typedef __attribute__((ext_vector_type(8))) short short8v;
typedef __attribute__((ext_vector_type(4))) short short4v;
typedef __attribute__((ext_vector_type(4))) float f32x4;

__device__ __forceinline__ float wave_sum(float v) {
#pragma unroll
  for (int off = 32; off; off >>= 1) v += __shfl_xor(v, off);
  return v;
}
__device__ __forceinline__ unsigned short f2bf(float x) {
  __hip_bfloat16 h = __float2bfloat16(x);
  return *reinterpret_cast<unsigned short*>(&h);
}

// global -> LDS async 16B (per-lane global addr, wave-uniform LDS base + lane*16)
__device__ __forceinline__ void gload16(const void* g, void* l) {
  __builtin_amdgcn_global_load_lds(
      (const __attribute__((address_space(1))) unsigned int*)g,
      (__attribute__((address_space(3))) unsigned int*)l, 16, 0, 0);
}

// ---------------------------------------------------------------------------
// Combined weight prep for the eight 512x512 slabs. grid (16,16,48).
struct Srcs8 { const float* s[8]; };
__global__ __launch_bounds__(256)
void wprep8_kernel(Srcs8 srcs, bf16* __restrict__ wt) {
  const int z = blockIdx.z;
  const int which = z & 7, l = z >> 3;
  const long long baseT[8] = {0, 0, 0, 18LL*SQC, 24LL*SQC, 30LL*SQC, 30LL*SQC, 42LL*SQC};
  const long long lstrT[8] = {3LL*SQC, 3LL*SQC, 3LL*SQC, SQC, SQC, 2LL*SQC, 2LL*SQC, SQC};
  const int rowOffT[8] = {0, 512, 1024, 0, 0, 0, 512, 0};

  __shared__ float t[32][33];
  const float* W = srcs.s[which] + (size_t)l * SQC;
  bf16* dst = wt + baseT[which] + (size_t)l * lstrT[which] + (size_t)rowOffT[which] * HD;
  const int n0 = blockIdx.x * 32, k0 = blockIdx.y * 32;
  const int tx = threadIdx.x & 31, ty = threadIdx.x >> 5;
#pragma unroll
  for (int j = 0; j < 4; ++j)
    t[ty + j * 8][tx] = W[(size_t)(k0 + ty + j * 8) * HD + n0 + tx];
  __syncthreads();
#pragma unroll
  for (int j = 0; j < 4; ++j)
    dst[(size_t)(n0 + ty + j * 8) * HD + k0 + tx] = __float2bfloat16(t[tx][ty + j * 8]);
}

// generic transpose prep for c1 (512x1024) and c2 (1024x512)
__global__ __launch_bounds__(256)
void wprep_kernel(const float* __restrict__ W, bf16* __restrict__ Wt, int Kd, int Nd) {
  __shared__ float t[32][33];
  const size_t src = (size_t)blockIdx.z * Kd * Nd;
  const int n0 = blockIdx.x * 32, k0 = blockIdx.y * 32;
  const int tx = threadIdx.x & 31, ty = threadIdx.x >> 5;
#pragma unroll
  for (int j = 0; j < 4; ++j)
    t[ty + j * 8][tx] = W[src + (size_t)(k0 + ty + j * 8) * Nd + n0 + tx];
  __syncthreads();
#pragma unroll
  for (int j = 0; j < 4; ++j)
    Wt[src + (size_t)(n0 + ty + j * 8) * Kd + k0 + tx] = __float2bfloat16(t[tx][ty + j * 8]);
}

// merged bias concats
__global__ __launch_bounds__(256)
void bcat2_kernel(const float* __restrict__ b0, const float* __restrict__ b1,
                  const float* __restrict__ b2, const float* __restrict__ c0,
                  const float* __restrict__ c1, float* __restrict__ outS,
                  float* __restrict__ outKV) {
  const int l = blockIdx.x;
  if (blockIdx.y == 0) {
    for (int i = threadIdx.x; i < 1536; i += 256) {
      const int seg = i >> 9, off = i & 511;
      const float* src = seg == 0 ? b0 : (seg == 1 ? b1 : b2);
      outS[(size_t)l * 1536 + i] = src[(size_t)l * 512 + off];
    }
  } else {
    for (int i = threadIdx.x; i < 1024; i += 256) {
      const float* src = (i >> 9) == 0 ? c0 : c1;
      outKV[(size_t)l * 1024 + i] = src[(size_t)l * 512 + (i & 511)];
    }
  }
}

__global__ __launch_bounds__(256)
void cvtbf16_kernel(const float* __restrict__ in, unsigned short* __restrict__ out) {
  const int i = (blockIdx.x * 256 + threadIdx.x) * 4;
  float4 v = *(const float4*)(in + i);
  out[i + 0] = f2bf(v.x); out[i + 1] = f2bf(v.y);
  out[i + 2] = f2bf(v.z); out[i + 3] = f2bf(v.w);
}

__global__ __launch_bounds__(256)
void embed_pe_kernel(const int* __restrict__ idx, const float* __restrict__ emb,
                     float* __restrict__ x, unsigned short* __restrict__ xb) {
  const int row = blockIdx.x;
  const int t = row & (TT - 1);
  const int tok = idx[row];
  const float cdiv = -0.017988946009466842f;  // -ln(10000)/512
#pragma unroll
  for (int e0 = 0; e0 < 2; ++e0) {
    const int e = threadIdx.x + e0 * 256;
    const float div = __expf((float)(e & ~1) * cdiv);
    const float ang = (float)t * div;
    const float pe = (e & 1) ? cosf(ang) : sinf(ang);
    const float v = emb[(size_t)tok * HD + e] + pe;
    x[(size_t)row * HD + e] = v;
    xb[(size_t)row * HD + e] = f2bf(v);
  }
}

// ---------------------------------------------------------------------------
// bf16 MFMA GEMM body: 64x64 tile, 4 waves, global_load_lds staging (no
// ds_writes), double-buffered LDS, ONE barrier per 64-K step.
// Swizzle per rule #21: linear LDS dest; global source chunk (l&7)^(l>>3)
// (inverse swizzle); reads XOR with (row&7)<<4 land on the right data.
__device__ __forceinline__ void gemm_compute(const char* As, const char* Bs,
                                             int wm, int wn, int lane,
                                             f32x4 (&acc)[2][2]) {
  const int rsw = (lane & 7) << 4;
  const int csel = (lane >> 4) * 16;
  short8v af[2][2], bfr[2][2];
#pragma unroll
  for (int m = 0; m < 2; ++m)
#pragma unroll
    for (int kk = 0; kk < 2; ++kk) {
      const int row = wm * 32 + m * 16 + (lane & 15);
      af[m][kk] = *(const short8v*)(As + row * 128 + ((kk * 64 + csel) ^ rsw));
    }
#pragma unroll
  for (int n = 0; n < 2; ++n)
#pragma unroll
    for (int kk = 0; kk < 2; ++kk) {
      const int row = wn * 32 + n * 16 + (lane & 15);
      bfr[n][kk] = *(const short8v*)(Bs + row * 128 + ((kk * 64 + csel) ^ rsw));
    }
#pragma unroll
  for (int m = 0; m < 2; ++m)
#pragma unroll
    for (int n = 0; n < 2; ++n) {
      acc[m][n] = __builtin_amdgcn_mfma_f32_16x16x32_bf16(af[m][0], bfr[n][0], acc[m][n], 0, 0, 0);
      acc[m][n] = __builtin_amdgcn_mfma_f32_16x16x32_bf16(af[m][1], bfr[n][1], acc[m][n], 0, 0, 0);
    }
}

template<int OUT_BF16, int RELU, int ADDRES>
__device__ __forceinline__
void mgemm_body(const bf16* __restrict__ A, const bf16* __restrict__ Bt,
                const float* __restrict__ bias, const float* __restrict__ res,
                float* __restrict__ Cf, unsigned short* __restrict__ Cb,
                int N, int K, int m0, int n0, char* As, char* Bs) {
  const int tid = threadIdx.x;
  const int w = tid >> 6, lane = tid & 63;
  const int wm = w >> 1, wn = w & 1;
  const int lrow = lane >> 3;            // 0..7
  const int lchk = (lane & 7) ^ lrow;    // inverse-swizzled source chunk

  // wave w stages A rows [w*16, w*16+16) and B rows likewise; 2 gload16 each.
  const bf16* ga0 = A + (size_t)(m0 + w * 16 + lrow) * K + lchk * 8;
  const bf16* ga1 = ga0 + (size_t)8 * K;
  const bf16* gb0 = Bt + (size_t)(n0 + w * 16 + lrow) * K + lchk * 8;
  const bf16* gb1 = gb0 + (size_t)8 * K;

  f32x4 acc[2][2] = {};
  const int NT = K >> 6;

  auto issue = [&](int t, int buf) {
    char* Ab = As + buf * 8192;
    char* Bb = Bs + buf * 8192;
    gload16(ga0 + t * 64, Ab + (w * 16) * 128);
    gload16(ga1 + t * 64, Ab + (w * 16 + 8) * 128);
    gload16(gb0 + t * 64, Bb + (w * 16) * 128);
    gload16(gb1 + t * 64, Bb + (w * 16 + 8) * 128);
  };

  issue(0, 0);
  for (int t = 0; t < NT; ++t) {
    __syncthreads();   // compiler drains vmcnt before barrier: buf[t&1] ready,
                       // and iter t-2's reads of buf[t&1] are complete.
    if (t + 1 < NT) issue(t + 1, (t + 1) & 1);  // flies under compute
    gemm_compute(As + (t & 1) * 8192, Bs + (t & 1) * 8192, wm, wn, lane, acc);
  }

  const int crow = (lane >> 4) * 4;
  const int ccol = lane & 15;
#pragma unroll
  for (int m = 0; m < 2; ++m)
#pragma unroll
    for (int n = 0; n < 2; ++n) {
      const int gr = m0 + wm * 32 + m * 16 + crow;
      const int gc = n0 + wn * 32 + n * 16 + ccol;
      const float bs = bias[gc];
#pragma unroll
      for (int r = 0; r < 4; ++r) {
        float v = acc[m][n][r] + bs;
        if (RELU) v = fmaxf(v, 0.f);
        if (ADDRES) v += res[(size_t)(gr + r) * N + gc];
        if (OUT_BF16) Cb[(size_t)(gr + r) * N + gc] = f2bf(v);
        else          Cf[(size_t)(gr + r) * N + gc] = v;
      }
    }
}

template<int OUT_BF16, int RELU, int ADDRES>
__global__ __launch_bounds__(256)
void mgemm_kernel(const bf16* __restrict__ A, const bf16* __restrict__ Bt,
                  const float* __restrict__ bias, const float* __restrict__ res,
                  float* __restrict__ Cf, unsigned short* __restrict__ Cb,
                  int N, int K) {
  __shared__ __attribute__((aligned(16))) char As[2 * 64 * 128];
  __shared__ __attribute__((aligned(16))) char Bs[2 * 64 * 128];
  mgemm_body<OUT_BF16, RELU, ADDRES>(A, Bt, bias, res, Cf, Cb, N, K,
                                     blockIdx.x * 64, blockIdx.y * 64, As, Bs);
}

// merged eaq (y<8) + eakv (y>=8) dispatch; K=512 both
__global__ __launch_bounds__(256)
void mgemm_cross_kernel(const bf16* __restrict__ A1, const bf16* __restrict__ B1,
                        const float* __restrict__ bias1, unsigned short* __restrict__ C1,
                        const bf16* __restrict__ A2, const bf16* __restrict__ B2,
                        const float* __restrict__ bias2, unsigned short* __restrict__ C2) {
  __shared__ __attribute__((aligned(16))) char As[2 * 64 * 128];
  __shared__ __attribute__((aligned(16))) char Bs[2 * 64 * 128];
  if (blockIdx.y < 8)
    mgemm_body<1, 0, 0>(A1, B1, bias1, nullptr, nullptr, C1, 512, 512,
                        blockIdx.x * 64, blockIdx.y * 64, As, Bs);
  else
    mgemm_body<1, 0, 0>(A2, B2, bias2, nullptr, nullptr, C2, 1024, 512,
                        blockIdx.x * 64, (blockIdx.y - 8) * 64, As, Bs);
}

// ---------------------------------------------------------------------------
// MFMA flash attention v5 (R8-proven): per-wave strip assignment for causal
// balance; register prefetch of next K/V/mask tile; additive pad-mask bias;
// diagonal-only causal compare; setprio around MFMA clusters.
template<int CAUSAL>
__global__ __launch_bounds__(512)
void mattn_kernel(const unsigned short* __restrict__ q, const unsigned short* __restrict__ kgl,
                  const unsigned short* __restrict__ vgl, unsigned short* __restrict__ ctx,
                  const int* __restrict__ idx, const unsigned char* __restrict__ emask,
                  int qstride, int kvstride) {
  __shared__ __attribute__((aligned(16))) unsigned short kt[64 * 64];    // [key][d] swz
  __shared__ __attribute__((aligned(16))) unsigned short vt[64 * 64];    // [d][key] swz
  __shared__ __attribute__((aligned(16))) unsigned short pl[8][16 * 64]; // per-wave P swz
  __shared__ float km[64];                                               // pad-mask bias

  const int bh = blockIdx.x;
  const int b = bh >> 3, h = bh & 7;
  const int tid = threadIdx.x, w = tid >> 6, lane = tid & 63;
  const int l4 = lane & 15, g = lane >> 4;

  int qb_w;
  if (CAUSAL) {
    const int strip = (w < 4) ? blockIdx.y : 7 - blockIdx.y;
    qb_w = strip * 64 + (w & 3) * 16;
  } else {
    qb_w = blockIdx.y * 128 + w * 16;
  }
  const int kvEnd = CAUSAL ? (8 - blockIdx.y) * 64 : TT;

  const unsigned short* qp = q + (size_t)(b * TT + qb_w + l4) * qstride + h * DK + g * 8;
  short8v aq0 = *(const short8v*)qp;
  short8v aq1 = *(const short8v*)(qp + 32);

  const int sr_k = tid >> 3, sc8 = tid & 7;
  const unsigned short* kbp = kgl + (size_t)(b * TT + sr_k) * kvstride + h * DK + sc8 * 8;
  const int k2 = (tid & 31) * 2, d4 = (tid >> 5) * 4;
  const unsigned short* vbp0 = vgl + (size_t)(b * TT + k2) * kvstride + h * DK + d4;
  const unsigned short* vbp1 = vbp0 + kvstride;

  short8v rk = *(const short8v*)kbp;
  short4v rv0 = *(const short4v*)vbp0;
  short4v rv1 = *(const short4v*)vbp1;
  float mreg = 0.f;
  if (tid < 64) {
    const int kp = b * TT + tid;
    mreg = (CAUSAL ? (idx[kp] == 0) : (emask[kp] != 0)) ? -1e9f : 0.f;
  }

  float m_r[4], l_r[4];
  f32x4 acc_o[4];
#pragma unroll
  for (int r = 0; r < 4; ++r) { m_r[r] = -1e30f; l_r[r] = 0.f; }
#pragma unroll
  for (int f = 0; f < 4; ++f) acc_o[f] = (f32x4){0.f, 0.f, 0.f, 0.f};

  for (int kt0 = 0; kt0 < kvEnd; kt0 += 64) {
    __syncthreads();   // previous tile fully consumed
    if (tid < 64) km[tid] = mreg;
    *(short8v*)((char*)kt + sr_k * 128 + ((sc8 * 16) ^ ((sr_k & 7) << 4))) = rk;
#pragma unroll
    for (int j = 0; j < 4; ++j) {
      const int d = d4 + j;
      const unsigned pk = ((unsigned)(unsigned short)rv0[j]) | (((unsigned)(unsigned short)rv1[j]) << 16);
      *(unsigned*)((char*)vt + d * 128 + ((k2 * 2) ^ ((d & 7) << 4))) = pk;
    }
    __syncthreads();

    if (kt0 + 64 < kvEnd) {
      const size_t off = (size_t)(kt0 + 64) * kvstride;
      rk = *(const short8v*)(kbp + off);
      rv0 = *(const short4v*)(vbp0 + off);
      rv1 = *(const short4v*)(vbp1 + off);
      if (tid < 64) {
        const int kp = b * TT + kt0 + 64 + tid;
        mreg = (CAUSAL ? (idx[kp] == 0) : (emask[kp] != 0)) ? -1e9f : 0.f;
      }
    }

    if (!(CAUSAL && kt0 > qb_w + 15)) {
      const bool diag = CAUSAL && (kt0 + 64 > qb_w);

      f32x4 s4[4];
      __builtin_amdgcn_s_setprio(1);
#pragma unroll
      for (int f = 0; f < 4; ++f) {
        const int krow = f * 16 + l4;
        const int sw = (krow & 7) << 4;
        short8v bk0 = *(const short8v*)((const char*)kt + krow * 128 + ((g * 16) ^ sw));
        short8v bk1 = *(const short8v*)((const char*)kt + krow * 128 + ((64 + g * 16) ^ sw));
        f32x4 a = {};
        a = __builtin_amdgcn_mfma_f32_16x16x32_bf16(aq0, bk0, a, 0, 0, 0);
        a = __builtin_amdgcn_mfma_f32_16x16x32_bf16(aq1, bk1, a, 0, 0, 0);
        s4[f] = a;
      }
      __builtin_amdgcn_s_setprio(0);

      float kmb[4];
#pragma unroll
      for (int f = 0; f < 4; ++f) kmb[f] = km[f * 16 + l4];

      float sc_r[4];
#pragma unroll
      for (int r = 0; r < 4; ++r) {
        const int qpos = qb_w + g * 4 + r;
        float sf[4];
#pragma unroll
        for (int f = 0; f < 4; ++f) sf[f] = fmaf(s4[f][r], 0.125f, kmb[f]);
        if (diag) {
#pragma unroll
          for (int f = 0; f < 4; ++f) {
            const int kpos = kt0 + f * 16 + l4;
            sf[f] = (kpos > qpos) ? -1e9f : sf[f];
          }
        }
        float mx = fmaxf(fmaxf(sf[0], sf[1]), fmaxf(sf[2], sf[3]));
#pragma unroll
        for (int off = 8; off; off >>= 1) mx = fmaxf(mx, __shfl_xor(mx, off));
        const float mn = fmaxf(m_r[r], mx);
        const float sc = __expf(m_r[r] - mn);
        m_r[r] = mn;
        sc_r[r] = sc;
        float ps = 0.f;
        const int prow = g * 4 + r;
        const int psw = (prow & 7) << 4;
#pragma unroll
        for (int f = 0; f < 4; ++f) {
          const float p = __expf(sf[f] - mn);
          ps += p;
          *(unsigned short*)((char*)pl[w] + prow * 128 + ((f * 32 + l4 * 2) ^ psw)) = f2bf(p);
        }
#pragma unroll
        for (int off = 8; off; off >>= 1) ps += __shfl_xor(ps, off);
        l_r[r] = l_r[r] * sc + ps;
      }

#pragma unroll
      for (int f = 0; f < 4; ++f)
#pragma unroll
        for (int r = 0; r < 4; ++r) acc_o[f][r] *= sc_r[r];

      const int asw = (l4 & 7) << 4;
      short8v pa0 = *(const short8v*)((const char*)pl[w] + l4 * 128 + ((g * 16) ^ asw));
      short8v pa1 = *(const short8v*)((const char*)pl[w] + l4 * 128 + ((g * 16 + 64) ^ asw));
      __builtin_amdgcn_s_setprio(1);
#pragma unroll
      for (int f = 0; f < 4; ++f) {
        const int drow = f * 16 + l4;
        const int sw = (drow & 7) << 4;
        short8v vb0 = *(const short8v*)((const char*)vt + drow * 128 + ((g * 16) ^ sw));
        short8v vb1 = *(const short8v*)((const char*)vt + drow * 128 + ((g * 16 + 64) ^ sw));
        acc_o[f] = __builtin_amdgcn_mfma_f32_16x16x32_bf16(pa0, vb0, acc_o[f], 0, 0, 0);
        acc_o[f] = __builtin_amdgcn_mfma_f32_16x16x32_bf16(pa1, vb1, acc_o[f], 0, 0, 0);
      }
      __builtin_amdgcn_s_setprio(0);
    }
  }

  float rl[4];
#pragma unroll
  for (int r = 0; r < 4; ++r) rl[r] = 1.f / l_r[r];
#pragma unroll
  for (int f = 0; f < 4; ++f)
#pragma unroll
    for (int r = 0; r < 4; ++r) {
      const int row = qb_w + g * 4 + r;
      const int col = h * DK + f * 16 + l4;
      ctx[(size_t)(b * TT + row) * HD + col] = f2bf(acc_o[f][r] * rl[r]);
    }
}

// ---------------------------------------------------------------------------
// LayerNorm over v (residual already folded in by GEMM epilogue).
__global__ __launch_bounds__(256)
void ln2_kernel(const float* __restrict__ v, float* __restrict__ out,
                unsigned short* __restrict__ outb,
                const float* __restrict__ g, const float* __restrict__ bta) {
  const int row = blockIdx.x;
  const int tid = threadIdx.x;
  const int w = tid >> 6, lane = tid & 63;
  const size_t ro = (size_t)row * HD;

  float v0 = v[ro + tid];
  float v1 = v[ro + tid + 256];

  __shared__ float red[4];
  float s = wave_sum(v0 + v1);
  if (lane == 0) red[w] = s;
  __syncthreads();
  const float mean = (red[0] + red[1] + red[2] + red[3]) * (1.f / HD);
  __syncthreads();

  const float d0 = v0 - mean, d1 = v1 - mean;
  float qv = wave_sum(d0 * d0 + d1 * d1);
  if (lane == 0) red[w] = qv;
  __syncthreads();
  const float var = (red[0] + red[1] + red[2] + red[3]) * (1.f / HD);
  const float rstd = rsqrtf(var + 1e-5f);

  const float o0 = d0 * rstd * g[tid] + bta[tid];
  const float o1 = d1 * rstd * g[tid + 256] + bta[tid + 256];
  out[ro + tid] = o0;
  out[ro + tid + 256] = o1;
  outb[ro + tid] = f2bf(o0);
  outb[ro + tid + 256] = f2bf(o1);
}

// ---------------------------------------------------------------------------
extern "C" void kernel_launch(void* const* d_in, const int* in_sizes, int n_in,
                              void* d_out, int out_size, void* d_ws, size_t ws_size,
                              hipStream_t stream) {
  const int* idx = (const int*)d_in[0];
  const float* enc = (const float*)d_in[1];
  const unsigned char* emask = (const unsigned char*)d_in[2];
  const float* emb = (const float*)d_in[4];
  const float* sa_wq = (const float*)d_in[5];
  const float* sa_bq = (const float*)d_in[6];
  const float* sa_wk = (const float*)d_in[7];
  const float* sa_bk = (const float*)d_in[8];
  const float* sa_wv = (const float*)d_in[9];
  const float* sa_bv = (const float*)d_in[10];
  const float* sa_wo = (const float*)d_in[11];
  const float* sa_bo = (const float*)d_in[12];
  const float* ln1g = (const float*)d_in[13];
  const float* ln1b = (const float*)d_in[14];
  const float* ea_wq = (const float*)d_in[15];
  const float* ea_bq = (const float*)d_in[16];
  const float* ea_wk = (const float*)d_in[17];
  const float* ea_bk = (const float*)d_in[18];
  const float* ea_wv = (const float*)d_in[19];
  const float* ea_bv = (const float*)d_in[20];
  const float* ea_wo = (const float*)d_in[21];
  const float* ea_bo = (const float*)d_in[22];
  const float* ln2g = (const float*)d_in[23];
  const float* ln2b = (const float*)d_in[24];
  const float* c1w = (const float*)d_in[25];
  const float* c1b = (const float*)d_in[26];
  const float* c2w = (const float*)d_in[27];
  const float* c2b = (const float*)d_in[28];
  const float* ln3g = (const float*)d_in[29];
  const float* ln3b = (const float*)d_in[30];

  const size_t MH = (size_t)MROWS * HD;   // 2,097,152
  const size_t SQ = (size_t)SQC;
  char* ws = (char*)d_ws;
  float*          x    = (float*)(ws + 0);                    // 8 MB
  unsigned short* xb   = (unsigned short*)(ws + (8u << 20));  // 4 MB
  unsigned short* qkvb = (unsigned short*)(ws + (12u << 20)); // 12 MB [4096][1536]
  unsigned short* qcb  = (unsigned short*)(ws + (24u << 20)); // 4 MB
  unsigned short* kvb  = (unsigned short*)(ws + (28u << 20)); // 8 MB [4096][1024]
  unsigned short* cxb  = (unsigned short*)(ws + (36u << 20)); // 4 MB
  float*          yb   = (float*)(ws + (40u << 20));          // 8 MB
  unsigned short* encb = (unsigned short*)(ws + (56u << 20)); // 4 MB
  bf16*           wt   = (bf16*)(ws + (60u << 20));           // 37.75 MB
  float*          bcS  = (float*)(ws + (98u << 20));          // [6][1536]
  float*          bcKV = (float*)(ws + (99u << 20));          // [6][1024]
  unsigned short* hb   = qkvb;  // FFN hidden [4096][1024] aliases qkvb

  bf16* t_saqkv = wt;             // [6][1536][512]
  bf16* t_sao   = wt + 18 * SQ;   // [6][512][512]
  bf16* t_eaq   = wt + 24 * SQ;
  bf16* t_eakv  = wt + 30 * SQ;   // [6][1024][512]
  bf16* t_eao   = wt + 42 * SQ;
  bf16* t_c1    = wt + 48 * SQ;   // [6][1024][512]
  bf16* t_c2    = wt + 60 * SQ;   // [6][512][1024]

  const dim3 blk(256);
  const dim3 blk512(512);
  const dim3 gQKV(MROWS / 64, 1536 / 64);   // 1536 blocks
  const dim3 g1024(MROWS / 64, 1024 / 64);  // 1024 blocks
  const dim3 g512(MROWS / 64, 512 / 64);    // 512 blocks
  const dim3 gCross(MROWS / 64, 24);        // merged eaq+eakv
  const dim3 attng(NB * NHD, 4);            // both attn variants

  Srcs8 s8;
  s8.s[0] = sa_wq; s8.s[1] = sa_wk; s8.s[2] = sa_wv; s8.s[3] = sa_wo;
  s8.s[4] = ea_wq; s8.s[5] = ea_wk; s8.s[6] = ea_wv; s8.s[7] = ea_wo;
  wprep8_kernel<<<dim3(16, 16, 48), blk, 0, stream>>>(s8, wt);
  wprep_kernel<<<dim3(32, 16, NL), blk, 0, stream>>>(c1w, t_c1, HD, DFFN);
  wprep_kernel<<<dim3(16, 32, NL), blk, 0, stream>>>(c2w, t_c2, DFFN, HD);
  bcat2_kernel<<<dim3(NL, 2), blk, 0, stream>>>(sa_bq, sa_bk, sa_bv, ea_bk, ea_bv, bcS, bcKV);
  cvtbf16_kernel<<<MH / 1024, blk, 0, stream>>>(enc, encb);

  embed_pe_kernel<<<MROWS, blk, 0, stream>>>(idx, emb, x, xb);

  for (int l = 0; l < NL; ++l) {
    const size_t b512 = (size_t)l * HD;
    const size_t bFF = (size_t)l * DFFN;
    float* lnout = (l == NL - 1) ? (float*)d_out : x;

    // ---- self attention ----
    mgemm_kernel<1, 0, 0><<<gQKV, blk, 0, stream>>>(
        (const bf16*)xb, t_saqkv + (size_t)l * 3 * SQ, bcS + (size_t)l * 1536,
        nullptr, nullptr, qkvb, 1536, HD);
    mattn_kernel<1><<<attng, blk512, 0, stream>>>(qkvb, qkvb + 512, qkvb + 1024, cxb,
                                                  idx, emask, 1536, 1536);
    mgemm_kernel<0, 0, 1><<<g512, blk, 0, stream>>>(
        (const bf16*)cxb, t_sao + (size_t)l * SQ, sa_bo + b512, x, yb, nullptr, HD, HD);
    ln2_kernel<<<MROWS, blk, 0, stream>>>(yb, x, xb, ln1g + b512, ln1b + b512);

    // ---- cross attention ----
    mgemm_cross_kernel<<<gCross, blk, 0, stream>>>(
        (const bf16*)xb, t_eaq + (size_t)l * SQ, ea_bq + b512, qcb,
        (const bf16*)encb, t_eakv + (size_t)l * 2 * SQ, bcKV + (size_t)l * 1024, kvb);
    mattn_kernel<0><<<attng, blk512, 0, stream>>>(qcb, kvb, kvb + 512, cxb,
                                                  idx, emask, 512, 1024);
    mgemm_kernel<0, 0, 1><<<g512, blk, 0, stream>>>(
        (const bf16*)cxb, t_eao + (size_t)l * SQ, ea_bo + b512, x, yb, nullptr, HD, HD);
    ln2_kernel<<<MROWS, blk, 0, stream>>>(yb, x, xb, ln2g + b512, ln2b + b512);

    // ---- FFN ----
    mgemm_kernel<1, 1, 0><<<g1024, blk, 0, stream>>>(
        (const bf16*)xb, t_c1 + (size_t)l * 2 * SQ, c1b + bFF, nullptr, nullptr, hb, DFFN, HD);
    mgemm_kernel<0, 0, 1><<<g512, blk, 0, stream>>>(
        (const bf16*)hb, t_c2 + (size_t)l * 2 * SQ, c2b + b512, x, yb, nullptr, HD, DFFN);
    ln2_kernel<<<MROWS, blk, 0, stream>>>(yb, lnout, xb, ln3g + b512, ln3b + b512);
  }
}

// Round 11
// 819.996 us; speedup vs baseline: 1.0352x; 1.0352x over previous
//
#include <hip/hip_runtime.h>
#include <hip/hip_bf16.h>
#include <math.h>

#define NL   6
#define HD   512
#define NHD  8
#define DK   64
#define DFFN 1024
#define NB   8
#define TT   512
#define MROWS (NB*TT)   // 4096
#define SQC  262144     // 512*512

typedef __hip_bfloat16 bf16;
typedef __attribute__((ext_vector_type(8))) short short8v;
typedef __attribute__((ext_vector_type(4))) short short4v;
typedef __attribute__((ext_vector_type(4))) float f32x4;

__device__ __forceinline__ float wave_sum(float v) {
#pragma unroll
  for (int off = 32; off; off >>= 1) v += __shfl_xor(v, off);
  return v;
}
__device__ __forceinline__ unsigned short f2bf(float x) {
  __hip_bfloat16 h = __float2bfloat16(x);
  return *reinterpret_cast<unsigned short*>(&h);
}
__device__ __forceinline__ float bf2f(unsigned short u) {
  return __uint_as_float(((unsigned)u) << 16);
}

// ---------------------------------------------------------------------------
// Combined weight prep for the eight 512x512 slabs. grid (16,16,48).
struct Srcs8 { const float* s[8]; };
__global__ __launch_bounds__(256)
void wprep8_kernel(Srcs8 srcs, bf16* __restrict__ wt) {
  const int z = blockIdx.z;
  const int which = z & 7, l = z >> 3;
  const long long baseT[8] = {0, 0, 0, 18LL*SQC, 24LL*SQC, 30LL*SQC, 30LL*SQC, 42LL*SQC};
  const long long lstrT[8] = {3LL*SQC, 3LL*SQC, 3LL*SQC, SQC, SQC, 2LL*SQC, 2LL*SQC, SQC};
  const int rowOffT[8] = {0, 512, 1024, 0, 0, 0, 512, 0};

  __shared__ float t[32][33];
  const float* W = srcs.s[which] + (size_t)l * SQC;
  bf16* dst = wt + baseT[which] + (size_t)l * lstrT[which] + (size_t)rowOffT[which] * HD;
  const int n0 = blockIdx.x * 32, k0 = blockIdx.y * 32;
  const int tx = threadIdx.x & 31, ty = threadIdx.x >> 5;
#pragma unroll
  for (int j = 0; j < 4; ++j)
    t[ty + j * 8][tx] = W[(size_t)(k0 + ty + j * 8) * HD + n0 + tx];
  __syncthreads();
#pragma unroll
  for (int j = 0; j < 4; ++j)
    dst[(size_t)(n0 + ty + j * 8) * HD + k0 + tx] = __float2bfloat16(t[tx][ty + j * 8]);
}

// generic transpose prep for c1 (512x1024) and c2 (1024x512)
__global__ __launch_bounds__(256)
void wprep_kernel(const float* __restrict__ W, bf16* __restrict__ Wt, int Kd, int Nd) {
  __shared__ float t[32][33];
  const size_t src = (size_t)blockIdx.z * Kd * Nd;
  const int n0 = blockIdx.x * 32, k0 = blockIdx.y * 32;
  const int tx = threadIdx.x & 31, ty = threadIdx.x >> 5;
#pragma unroll
  for (int j = 0; j < 4; ++j)
    t[ty + j * 8][tx] = W[src + (size_t)(k0 + ty + j * 8) * Nd + n0 + tx];
  __syncthreads();
#pragma unroll
  for (int j = 0; j < 4; ++j)
    Wt[src + (size_t)(n0 + ty + j * 8) * Kd + k0 + tx] = __float2bfloat16(t[tx][ty + j * 8]);
}

// merged bias concats
__global__ __launch_bounds__(256)
void bcat2_kernel(const float* __restrict__ b0, const float* __restrict__ b1,
                  const float* __restrict__ b2, const float* __restrict__ c0,
                  const float* __restrict__ c1, float* __restrict__ outS,
                  float* __restrict__ outKV) {
  const int l = blockIdx.x;
  if (blockIdx.y == 0) {
    for (int i = threadIdx.x; i < 1536; i += 256) {
      const int seg = i >> 9, off = i & 511;
      const float* src = seg == 0 ? b0 : (seg == 1 ? b1 : b2);
      outS[(size_t)l * 1536 + i] = src[(size_t)l * 512 + off];
    }
  } else {
    for (int i = threadIdx.x; i < 1024; i += 256) {
      const float* src = (i >> 9) == 0 ? c0 : c1;
      outKV[(size_t)l * 1024 + i] = src[(size_t)l * 512 + (i & 511)];
    }
  }
}

__global__ __launch_bounds__(256)
void cvtbf16_kernel(const float* __restrict__ in, unsigned short* __restrict__ out) {
  const int i = (blockIdx.x * 256 + threadIdx.x) * 4;
  float4 v = *(const float4*)(in + i);
  out[i + 0] = f2bf(v.x); out[i + 1] = f2bf(v.y);
  out[i + 2] = f2bf(v.z); out[i + 3] = f2bf(v.w);
}

__global__ __launch_bounds__(256)
void embed_pe_kernel(const int* __restrict__ idx, const float* __restrict__ emb,
                     float* __restrict__ x, unsigned short* __restrict__ xb) {
  const int row = blockIdx.x;
  const int t = row & (TT - 1);
  const int tok = idx[row];
  const float cdiv = -0.017988946009466842f;  // -ln(10000)/512
#pragma unroll
  for (int e0 = 0; e0 < 2; ++e0) {
    const int e = threadIdx.x + e0 * 256;
    const float div = __expf((float)(e & ~1) * cdiv);
    const float ang = (float)t * div;
    const float pe = (e & 1) ? cosf(ang) : sinf(ang);
    const float v = emb[(size_t)tok * HD + e] + pe;
    x[(size_t)row * HD + e] = v;
    xb[(size_t)row * HD + e] = f2bf(v);
  }
}

// ---------------------------------------------------------------------------
// bf16 MFMA GEMM body (R8-proven): 64x64 tile, 4 waves, reg-staged LDS,
// XOR swizzle, 2-phase per 128-K. ADDRES fuses f32 residual add.
__device__ __forceinline__ void gemm_compute(const char* As, const char* Bs,
                                             int wm, int wn, int lane,
                                             f32x4 (&acc)[2][2]) {
  const int rsw = (lane & 7) << 4;
  const int csel = (lane >> 4) * 16;
  short8v af[2][2], bfr[2][2];
#pragma unroll
  for (int m = 0; m < 2; ++m)
#pragma unroll
    for (int kk = 0; kk < 2; ++kk) {
      const int row = wm * 32 + m * 16 + (lane & 15);
      af[m][kk] = *(const short8v*)(As + row * 128 + ((kk * 64 + csel) ^ rsw));
    }
#pragma unroll
  for (int n = 0; n < 2; ++n)
#pragma unroll
    for (int kk = 0; kk < 2; ++kk) {
      const int row = wn * 32 + n * 16 + (lane & 15);
      bfr[n][kk] = *(const short8v*)(Bs + row * 128 + ((kk * 64 + csel) ^ rsw));
    }
#pragma unroll
  for (int m = 0; m < 2; ++m)
#pragma unroll
    for (int n = 0; n < 2; ++n) {
      acc[m][n] = __builtin_amdgcn_mfma_f32_16x16x32_bf16(af[m][0], bfr[n][0], acc[m][n], 0, 0, 0);
      acc[m][n] = __builtin_amdgcn_mfma_f32_16x16x32_bf16(af[m][1], bfr[n][1], acc[m][n], 0, 0, 0);
    }
}

template<int OUT_BF16, int RELU, int ADDRES>
__device__ __forceinline__
void mgemm_body(const bf16* __restrict__ A, const bf16* __restrict__ Bt,
                const float* __restrict__ bias, const float* __restrict__ res,
                float* __restrict__ Cf, unsigned short* __restrict__ Cb,
                int N, int K, int m0, int n0, char* As, char* Bs) {
  const int tid = threadIdx.x;
  const int w = tid >> 6, lane = tid & 63;
  const int wm = w >> 1, wn = w & 1;

  const int sr = w * 16 + (lane >> 3);
  const int scol = (lane & 7) * 16;
  const int swc = scol ^ ((sr & 7) << 4);
  const bf16* ga0 = A + (size_t)(m0 + sr) * K + (scol >> 1);
  const bf16* ga1 = A + (size_t)(m0 + sr + 8) * K + (scol >> 1);
  const bf16* gb0 = Bt + (size_t)(n0 + sr) * K + (scol >> 1);
  const bf16* gb1 = Bt + (size_t)(n0 + sr + 8) * K + (scol >> 1);
  char* la0 = As + sr * 128 + swc;
  char* la1 = As + (sr + 8) * 128 + swc;
  char* lb0 = Bs + sr * 128 + swc;
  char* lb1 = Bs + (sr + 8) * 128 + swc;

  f32x4 acc[2][2] = {};

  short8v ra0 = *(const short8v*)ga0, ra1 = *(const short8v*)ga1;
  short8v rb0 = *(const short8v*)gb0, rb1 = *(const short8v*)gb1;
  short8v sa0, sa1, sb0, sb1;

  for (int k0 = 0; k0 < K; k0 += 128) {
    __syncthreads();
    *(short8v*)la0 = ra0; *(short8v*)la1 = ra1;
    *(short8v*)lb0 = rb0; *(short8v*)lb1 = rb1;
    __syncthreads();
    sa0 = *(const short8v*)(ga0 + k0 + 64); sa1 = *(const short8v*)(ga1 + k0 + 64);
    sb0 = *(const short8v*)(gb0 + k0 + 64); sb1 = *(const short8v*)(gb1 + k0 + 64);
    gemm_compute(As, Bs, wm, wn, lane, acc);
    __syncthreads();
    *(short8v*)la0 = sa0; *(short8v*)la1 = sa1;
    *(short8v*)lb0 = sb0; *(short8v*)lb1 = sb1;
    __syncthreads();
    if (k0 + 128 < K) {
      ra0 = *(const short8v*)(ga0 + k0 + 128); ra1 = *(const short8v*)(ga1 + k0 + 128);
      rb0 = *(const short8v*)(gb0 + k0 + 128); rb1 = *(const short8v*)(gb1 + k0 + 128);
    }
    gemm_compute(As, Bs, wm, wn, lane, acc);
  }

  const int crow = (lane >> 4) * 4;
  const int ccol = lane & 15;
#pragma unroll
  for (int m = 0; m < 2; ++m)
#pragma unroll
    for (int n = 0; n < 2; ++n) {
      const int gr = m0 + wm * 32 + m * 16 + crow;
      const int gc = n0 + wn * 32 + n * 16 + ccol;
      const float bs = bias[gc];
#pragma unroll
      for (int r = 0; r < 4; ++r) {
        float v = acc[m][n][r] + bs;
        if (RELU) v = fmaxf(v, 0.f);
        if (ADDRES) v += res[(size_t)(gr + r) * N + gc];
        if (OUT_BF16) Cb[(size_t)(gr + r) * N + gc] = f2bf(v);
        else          Cf[(size_t)(gr + r) * N + gc] = v;
      }
    }
}

template<int OUT_BF16, int RELU, int ADDRES>
__global__ __launch_bounds__(256)
void mgemm_kernel(const bf16* __restrict__ A, const bf16* __restrict__ Bt,
                  const float* __restrict__ bias, const float* __restrict__ res,
                  float* __restrict__ Cf, unsigned short* __restrict__ Cb,
                  int N, int K) {
  __shared__ __attribute__((aligned(16))) char As[64 * 128];
  __shared__ __attribute__((aligned(16))) char Bs[64 * 128];
  mgemm_body<OUT_BF16, RELU, ADDRES>(A, Bt, bias, res, Cf, Cb, N, K,
                                     blockIdx.x * 64, blockIdx.y * 64, As, Bs);
}

// all-layer cross-KV precompute: grid (64, 96); y -> l = y/16, n-block = y%16
__global__ __launch_bounds__(256)
void mgemm_eakv_kernel(const bf16* __restrict__ A, const bf16* __restrict__ BtBase,
                       const float* __restrict__ biasBase, unsigned short* __restrict__ CBase) {
  __shared__ __attribute__((aligned(16))) char As[64 * 128];
  __shared__ __attribute__((aligned(16))) char Bs[64 * 128];
  const int l = blockIdx.y >> 4, ny = blockIdx.y & 15;
  mgemm_body<1, 0, 0>(A, BtBase + (size_t)l * 2 * SQC, biasBase + (size_t)l * 1024,
                      nullptr, nullptr, CBase + (size_t)l * MROWS * 1024,
                      1024, 512, blockIdx.x * 64, ny * 64, As, Bs);
}

// ---------------------------------------------------------------------------
// MFMA flash attention v5 (R8-proven): per-wave strip assignment for causal
// balance; register prefetch of next K/V/mask tile; additive pad-mask bias;
// diagonal-only causal compare; setprio around MFMA clusters.
template<int CAUSAL>
__global__ __launch_bounds__(512)
void mattn_kernel(const unsigned short* __restrict__ q, const unsigned short* __restrict__ kgl,
                  const unsigned short* __restrict__ vgl, unsigned short* __restrict__ ctx,
                  const int* __restrict__ idx, const unsigned char* __restrict__ emask,
                  int qstride, int kvstride) {
  __shared__ __attribute__((aligned(16))) unsigned short kt[64 * 64];    // [key][d] swz
  __shared__ __attribute__((aligned(16))) unsigned short vt[64 * 64];    // [d][key] swz
  __shared__ __attribute__((aligned(16))) unsigned short pl[8][16 * 64]; // per-wave P swz
  __shared__ float km[64];                                               // pad-mask bias

  const int bh = blockIdx.x;
  const int b = bh >> 3, h = bh & 7;
  const int tid = threadIdx.x, w = tid >> 6, lane = tid & 63;
  const int l4 = lane & 15, g = lane >> 4;

  int qb_w;
  if (CAUSAL) {
    const int strip = (w < 4) ? blockIdx.y : 7 - blockIdx.y;
    qb_w = strip * 64 + (w & 3) * 16;
  } else {
    qb_w = blockIdx.y * 128 + w * 16;
  }
  const int kvEnd = CAUSAL ? (8 - blockIdx.y) * 64 : TT;

  const unsigned short* qp = q + (size_t)(b * TT + qb_w + l4) * qstride + h * DK + g * 8;
  short8v aq0 = *(const short8v*)qp;
  short8v aq1 = *(const short8v*)(qp + 32);

  const int sr_k = tid >> 3, sc8 = tid & 7;
  const unsigned short* kbp = kgl + (size_t)(b * TT + sr_k) * kvstride + h * DK + sc8 * 8;
  const int k2 = (tid & 31) * 2, d4 = (tid >> 5) * 4;
  const unsigned short* vbp0 = vgl + (size_t)(b * TT + k2) * kvstride + h * DK + d4;
  const unsigned short* vbp1 = vbp0 + kvstride;

  short8v rk = *(const short8v*)kbp;
  short4v rv0 = *(const short4v*)vbp0;
  short4v rv1 = *(const short4v*)vbp1;
  float mreg = 0.f;
  if (tid < 64) {
    const int kp = b * TT + tid;
    mreg = (CAUSAL ? (idx[kp] == 0) : (emask[kp] != 0)) ? -1e9f : 0.f;
  }

  float m_r[4], l_r[4];
  f32x4 acc_o[4];
#pragma unroll
  for (int r = 0; r < 4; ++r) { m_r[r] = -1e30f; l_r[r] = 0.f; }
#pragma unroll
  for (int f = 0; f < 4; ++f) acc_o[f] = (f32x4){0.f, 0.f, 0.f, 0.f};

  for (int kt0 = 0; kt0 < kvEnd; kt0 += 64) {
    __syncthreads();   // previous tile fully consumed
    if (tid < 64) km[tid] = mreg;
    *(short8v*)((char*)kt + sr_k * 128 + ((sc8 * 16) ^ ((sr_k & 7) << 4))) = rk;
#pragma unroll
    for (int j = 0; j < 4; ++j) {
      const int d = d4 + j;
      const unsigned pk = ((unsigned)(unsigned short)rv0[j]) | (((unsigned)(unsigned short)rv1[j]) << 16);
      *(unsigned*)((char*)vt + d * 128 + ((k2 * 2) ^ ((d & 7) << 4))) = pk;
    }
    __syncthreads();

    if (kt0 + 64 < kvEnd) {
      const size_t off = (size_t)(kt0 + 64) * kvstride;
      rk = *(const short8v*)(kbp + off);
      rv0 = *(const short4v*)(vbp0 + off);
      rv1 = *(const short4v*)(vbp1 + off);
      if (tid < 64) {
        const int kp = b * TT + kt0 + 64 + tid;
        mreg = (CAUSAL ? (idx[kp] == 0) : (emask[kp] != 0)) ? -1e9f : 0.f;
      }
    }

    if (!(CAUSAL && kt0 > qb_w + 15)) {
      const bool diag = CAUSAL && (kt0 + 64 > qb_w);

      f32x4 s4[4];
      __builtin_amdgcn_s_setprio(1);
#pragma unroll
      for (int f = 0; f < 4; ++f) {
        const int krow = f * 16 + l4;
        const int sw = (krow & 7) << 4;
        short8v bk0 = *(const short8v*)((const char*)kt + krow * 128 + ((g * 16) ^ sw));
        short8v bk1 = *(const short8v*)((const char*)kt + krow * 128 + ((64 + g * 16) ^ sw));
        f32x4 a = {};
        a = __builtin_amdgcn_mfma_f32_16x16x32_bf16(aq0, bk0, a, 0, 0, 0);
        a = __builtin_amdgcn_mfma_f32_16x16x32_bf16(aq1, bk1, a, 0, 0, 0);
        s4[f] = a;
      }
      __builtin_amdgcn_s_setprio(0);

      float kmb[4];
#pragma unroll
      for (int f = 0; f < 4; ++f) kmb[f] = km[f * 16 + l4];

      float sc_r[4];
#pragma unroll
      for (int r = 0; r < 4; ++r) {
        const int qpos = qb_w + g * 4 + r;
        float sf[4];
#pragma unroll
        for (int f = 0; f < 4; ++f) sf[f] = fmaf(s4[f][r], 0.125f, kmb[f]);
        if (diag) {
#pragma unroll
          for (int f = 0; f < 4; ++f) {
            const int kpos = kt0 + f * 16 + l4;
            sf[f] = (kpos > qpos) ? -1e9f : sf[f];
          }
        }
        float mx = fmaxf(fmaxf(sf[0], sf[1]), fmaxf(sf[2], sf[3]));
#pragma unroll
        for (int off = 8; off; off >>= 1) mx = fmaxf(mx, __shfl_xor(mx, off));
        const float mn = fmaxf(m_r[r], mx);
        const float sc = __expf(m_r[r] - mn);
        m_r[r] = mn;
        sc_r[r] = sc;
        float ps = 0.f;
        const int prow = g * 4 + r;
        const int psw = (prow & 7) << 4;
#pragma unroll
        for (int f = 0; f < 4; ++f) {
          const float p = __expf(sf[f] - mn);
          ps += p;
          *(unsigned short*)((char*)pl[w] + prow * 128 + ((f * 32 + l4 * 2) ^ psw)) = f2bf(p);
        }
#pragma unroll
        for (int off = 8; off; off >>= 1) ps += __shfl_xor(ps, off);
        l_r[r] = l_r[r] * sc + ps;
      }

#pragma unroll
      for (int f = 0; f < 4; ++f)
#pragma unroll
        for (int r = 0; r < 4; ++r) acc_o[f][r] *= sc_r[r];

      const int asw = (l4 & 7) << 4;
      short8v pa0 = *(const short8v*)((const char*)pl[w] + l4 * 128 + ((g * 16) ^ asw));
      short8v pa1 = *(const short8v*)((const char*)pl[w] + l4 * 128 + ((g * 16 + 64) ^ asw));
      __builtin_amdgcn_s_setprio(1);
#pragma unroll
      for (int f = 0; f < 4; ++f) {
        const int drow = f * 16 + l4;
        const int sw = (drow & 7) << 4;
        short8v vb0 = *(const short8v*)((const char*)vt + drow * 128 + ((g * 16) ^ sw));
        short8v vb1 = *(const short8v*)((const char*)vt + drow * 128 + ((g * 16 + 64) ^ sw));
        acc_o[f] = __builtin_amdgcn_mfma_f32_16x16x32_bf16(pa0, vb0, acc_o[f], 0, 0, 0);
        acc_o[f] = __builtin_amdgcn_mfma_f32_16x16x32_bf16(pa1, vb1, acc_o[f], 0, 0, 0);
      }
      __builtin_amdgcn_s_setprio(0);
    }
  }

  float rl[4];
#pragma unroll
  for (int r = 0; r < 4; ++r) rl[r] = 1.f / l_r[r];
#pragma unroll
  for (int f = 0; f < 4; ++f)
#pragma unroll
    for (int r = 0; r < 4; ++r) {
      const int row = qb_w + g * 4 + r;
      const int col = h * DK + f * 16 + l4;
      ctx[(size_t)(b * TT + row) * HD + col] = f2bf(acc_o[f][r] * rl[r]);
    }
}

// ---------------------------------------------------------------------------
// LayerNorm over bf16 v (residual already folded in by GEMM epilogue).
__global__ __launch_bounds__(256)
void ln2_kernel(const unsigned short* __restrict__ v, float* __restrict__ out,
                unsigned short* __restrict__ outb,
                const float* __restrict__ g, const float* __restrict__ bta) {
  const int row = blockIdx.x;
  const int tid = threadIdx.x;
  const int w = tid >> 6, lane = tid & 63;
  const size_t ro = (size_t)row * HD;

  float v0 = bf2f(v[ro + tid]);
  float v1 = bf2f(v[ro + tid + 256]);

  __shared__ float red[4];
  float s = wave_sum(v0 + v1);
  if (lane == 0) red[w] = s;
  __syncthreads();
  const float mean = (red[0] + red[1] + red[2] + red[3]) * (1.f / HD);
  __syncthreads();

  const float d0 = v0 - mean, d1 = v1 - mean;
  float qv = wave_sum(d0 * d0 + d1 * d1);
  if (lane == 0) red[w] = qv;
  __syncthreads();
  const float var = (red[0] + red[1] + red[2] + red[3]) * (1.f / HD);
  const float rstd = rsqrtf(var + 1e-5f);

  const float o0 = d0 * rstd * g[tid] + bta[tid];
  const float o1 = d1 * rstd * g[tid + 256] + bta[tid + 256];
  out[ro + tid] = o0;
  out[ro + tid + 256] = o1;
  outb[ro + tid] = f2bf(o0);
  outb[ro + tid + 256] = f2bf(o1);
}

// ---------------------------------------------------------------------------
extern "C" void kernel_launch(void* const* d_in, const int* in_sizes, int n_in,
                              void* d_out, int out_size, void* d_ws, size_t ws_size,
                              hipStream_t stream) {
  const int* idx = (const int*)d_in[0];
  const float* enc = (const float*)d_in[1];
  const unsigned char* emask = (const unsigned char*)d_in[2];
  const float* emb = (const float*)d_in[4];
  const float* sa_wq = (const float*)d_in[5];
  const float* sa_bq = (const float*)d_in[6];
  const float* sa_wk = (const float*)d_in[7];
  const float* sa_bk = (const float*)d_in[8];
  const float* sa_wv = (const float*)d_in[9];
  const float* sa_bv = (const float*)d_in[10];
  const float* sa_wo = (const float*)d_in[11];
  const float* sa_bo = (const float*)d_in[12];
  const float* ln1g = (const float*)d_in[13];
  const float* ln1b = (const float*)d_in[14];
  const float* ea_wq = (const float*)d_in[15];
  const float* ea_bq = (const float*)d_in[16];
  const float* ea_wk = (const float*)d_in[17];
  const float* ea_bk = (const float*)d_in[18];
  const float* ea_wv = (const float*)d_in[19];
  const float* ea_bv = (const float*)d_in[20];
  const float* ea_wo = (const float*)d_in[21];
  const float* ea_bo = (const float*)d_in[22];
  const float* ln2g = (const float*)d_in[23];
  const float* ln2b = (const float*)d_in[24];
  const float* c1w = (const float*)d_in[25];
  const float* c1b = (const float*)d_in[26];
  const float* c2w = (const float*)d_in[27];
  const float* c2b = (const float*)d_in[28];
  const float* ln3g = (const float*)d_in[29];
  const float* ln3b = (const float*)d_in[30];

  const size_t MH = (size_t)MROWS * HD;   // 2,097,152
  const size_t SQ = (size_t)SQC;
  char* ws = (char*)d_ws;
  float*          x    = (float*)(ws + 0);                    // 8 MB
  unsigned short* xb   = (unsigned short*)(ws + (8u << 20));  // 4 MB
  unsigned short* qkvb = (unsigned short*)(ws + (12u << 20)); // 12 MB [4096][1536]
  unsigned short* qcb  = (unsigned short*)(ws + (24u << 20)); // 4 MB
  unsigned short* cxb  = (unsigned short*)(ws + (28u << 20)); // 4 MB
  unsigned short* ybb  = (unsigned short*)(ws + (32u << 20)); // 4 MB bf16 LN input
  unsigned short* encb = (unsigned short*)(ws + (36u << 20)); // 4 MB
  bf16*           wt   = (bf16*)(ws + (40u << 20));           // 37.75 MB
  float*          bcS  = (float*)(ws + (78u << 20));          // [6][1536]
  float*          bcKV = (float*)(ws + (79u << 20));          // [6][1024]
  unsigned short* kvb6 = (unsigned short*)(ws + (80u << 20)); // 48 MB [6][4096][1024]
  unsigned short* hb   = qkvb;  // FFN hidden [4096][1024] aliases qkvb

  bf16* t_saqkv = wt;             // [6][1536][512]
  bf16* t_sao   = wt + 18 * SQ;   // [6][512][512]
  bf16* t_eaq   = wt + 24 * SQ;
  bf16* t_eakv  = wt + 30 * SQ;   // [6][1024][512]
  bf16* t_eao   = wt + 42 * SQ;
  bf16* t_c1    = wt + 48 * SQ;   // [6][1024][512]
  bf16* t_c2    = wt + 60 * SQ;   // [6][512][1024]

  const dim3 blk(256);
  const dim3 blk512(512);
  const dim3 gQKV(MROWS / 64, 1536 / 64);   // 1536 blocks
  const dim3 g1024(MROWS / 64, 1024 / 64);  // 1024 blocks
  const dim3 g512(MROWS / 64, 512 / 64);    // 512 blocks
  const dim3 gEAKV(MROWS / 64, 96);         // 6144 blocks, all 6 layers
  const dim3 attng(NB * NHD, 4);            // both attn variants

  Srcs8 s8;
  s8.s[0] = sa_wq; s8.s[1] = sa_wk; s8.s[2] = sa_wv; s8.s[3] = sa_wo;
  s8.s[4] = ea_wq; s8.s[5] = ea_wk; s8.s[6] = ea_wv; s8.s[7] = ea_wo;
  wprep8_kernel<<<dim3(16, 16, 48), blk, 0, stream>>>(s8, wt);
  wprep_kernel<<<dim3(32, 16, NL), blk, 0, stream>>>(c1w, t_c1, HD, DFFN);
  wprep_kernel<<<dim3(16, 32, NL), blk, 0, stream>>>(c2w, t_c2, DFFN, HD);
  bcat2_kernel<<<dim3(NL, 2), blk, 0, stream>>>(sa_bq, sa_bk, sa_bv, ea_bk, ea_bv, bcS, bcKV);
  cvtbf16_kernel<<<MH / 1024, blk, 0, stream>>>(enc, encb);
  // all-layer cross K/V precompute (depends only on enc)
  mgemm_eakv_kernel<<<gEAKV, blk, 0, stream>>>((const bf16*)encb, t_eakv, bcKV, kvb6);

  embed_pe_kernel<<<MROWS, blk, 0, stream>>>(idx, emb, x, xb);

  for (int l = 0; l < NL; ++l) {
    const size_t b512 = (size_t)l * HD;
    const size_t bFF = (size_t)l * DFFN;
    float* lnout = (l == NL - 1) ? (float*)d_out : x;
    unsigned short* kvl = kvb6 + (size_t)l * MROWS * 1024;

    // ---- self attention ----
    mgemm_kernel<1, 0, 0><<<gQKV, blk, 0, stream>>>(
        (const bf16*)xb, t_saqkv + (size_t)l * 3 * SQ, bcS + (size_t)l * 1536,
        nullptr, nullptr, qkvb, 1536, HD);
    mattn_kernel<1><<<attng, blk512, 0, stream>>>(qkvb, qkvb + 512, qkvb + 1024, cxb,
                                                  idx, emask, 1536, 1536);
    mgemm_kernel<1, 0, 1><<<g512, blk, 0, stream>>>(
        (const bf16*)cxb, t_sao + (size_t)l * SQ, sa_bo + b512, x, nullptr, ybb, HD, HD);
    ln2_kernel<<<MROWS, blk, 0, stream>>>(ybb, x, xb, ln1g + b512, ln1b + b512);

    // ---- cross attention ----
    mgemm_kernel<1, 0, 0><<<g512, blk, 0, stream>>>(
        (const bf16*)xb, t_eaq + (size_t)l * SQ, ea_bq + b512, nullptr, nullptr, qcb, HD, HD);
    mattn_kernel<0><<<attng, blk512, 0, stream>>>(qcb, kvl, kvl + 512, cxb,
                                                  idx, emask, 512, 1024);
    mgemm_kernel<1, 0, 1><<<g512, blk, 0, stream>>>(
        (const bf16*)cxb, t_eao + (size_t)l * SQ, ea_bo + b512, x, nullptr, ybb, HD, HD);
    ln2_kernel<<<MROWS, blk, 0, stream>>>(ybb, x, xb, ln2g + b512, ln2b + b512);

    // ---- FFN ----
    mgemm_kernel<1, 1, 0><<<g1024, blk, 0, stream>>>(
        (const bf16*)xb, t_c1 + (size_t)l * 2 * SQ, c1b + bFF, nullptr, nullptr, hb, DFFN, HD);
    mgemm_kernel<1, 0, 1><<<g512, blk, 0, stream>>>(
        (const bf16*)hb, t_c2 + (size_t)l * 2 * SQ, c2b + b512, x, nullptr, ybb, HD, DFFN);
    ln2_kernel<<<MROWS, blk, 0, stream>>>(ybb, lnout, xb, ln3g + b512, ln3b + b512);
  }
}

// Round 12
// 799.580 us; speedup vs baseline: 1.0617x; 1.0255x over previous
//
#include <hip/hip_runtime.h>
#include <hip/hip_bf16.h>
#include <math.h>

#define NL   6
#define HD   512
#define NHD  8
#define DK   64
#define DFFN 1024
#define NB   8
#define TT   512
#define MROWS (NB*TT)   // 4096
#define SQC  262144     // 512*512

typedef __hip_bfloat16 bf16;
typedef __attribute__((ext_vector_type(8))) short short8v;
typedef __attribute__((ext_vector_type(4))) short short4v;
typedef __attribute__((ext_vector_type(4))) float f32x4;

__device__ __forceinline__ float wave_sum(float v) {
#pragma unroll
  for (int off = 32; off; off >>= 1) v += __shfl_xor(v, off);
  return v;
}
__device__ __forceinline__ unsigned short f2bf(float x) {
  __hip_bfloat16 h = __float2bfloat16(x);
  return *reinterpret_cast<unsigned short*>(&h);
}
__device__ __forceinline__ float bf2f(unsigned short u) {
  return __uint_as_float(((unsigned)u) << 16);
}

// ---------------------------------------------------------------------------
// Combined weight prep for the eight 512x512 slabs. grid (16,16,48).
struct Srcs8 { const float* s[8]; };
__global__ __launch_bounds__(256)
void wprep8_kernel(Srcs8 srcs, bf16* __restrict__ wt) {
  const int z = blockIdx.z;
  const int which = z & 7, l = z >> 3;
  const long long baseT[8] = {0, 0, 0, 18LL*SQC, 24LL*SQC, 30LL*SQC, 30LL*SQC, 42LL*SQC};
  const long long lstrT[8] = {3LL*SQC, 3LL*SQC, 3LL*SQC, SQC, SQC, 2LL*SQC, 2LL*SQC, SQC};
  const int rowOffT[8] = {0, 512, 1024, 0, 0, 0, 512, 0};

  __shared__ float t[32][33];
  const float* W = srcs.s[which] + (size_t)l * SQC;
  bf16* dst = wt + baseT[which] + (size_t)l * lstrT[which] + (size_t)rowOffT[which] * HD;
  const int n0 = blockIdx.x * 32, k0 = blockIdx.y * 32;
  const int tx = threadIdx.x & 31, ty = threadIdx.x >> 5;
#pragma unroll
  for (int j = 0; j < 4; ++j)
    t[ty + j * 8][tx] = W[(size_t)(k0 + ty + j * 8) * HD + n0 + tx];
  __syncthreads();
#pragma unroll
  for (int j = 0; j < 4; ++j)
    dst[(size_t)(n0 + ty + j * 8) * HD + k0 + tx] = __float2bfloat16(t[tx][ty + j * 8]);
}

// generic transpose prep for c1 (512x1024) and c2 (1024x512)
__global__ __launch_bounds__(256)
void wprep_kernel(const float* __restrict__ W, bf16* __restrict__ Wt, int Kd, int Nd) {
  __shared__ float t[32][33];
  const size_t src = (size_t)blockIdx.z * Kd * Nd;
  const int n0 = blockIdx.x * 32, k0 = blockIdx.y * 32;
  const int tx = threadIdx.x & 31, ty = threadIdx.x >> 5;
#pragma unroll
  for (int j = 0; j < 4; ++j)
    t[ty + j * 8][tx] = W[src + (size_t)(k0 + ty + j * 8) * Nd + n0 + tx];
  __syncthreads();
#pragma unroll
  for (int j = 0; j < 4; ++j)
    Wt[src + (size_t)(n0 + ty + j * 8) * Kd + k0 + tx] = __float2bfloat16(t[tx][ty + j * 8]);
}

// merged bias concats
__global__ __launch_bounds__(256)
void bcat2_kernel(const float* __restrict__ b0, const float* __restrict__ b1,
                  const float* __restrict__ b2, const float* __restrict__ c0,
                  const float* __restrict__ c1, float* __restrict__ outS,
                  float* __restrict__ outKV) {
  const int l = blockIdx.x;
  if (blockIdx.y == 0) {
    for (int i = threadIdx.x; i < 1536; i += 256) {
      const int seg = i >> 9, off = i & 511;
      const float* src = seg == 0 ? b0 : (seg == 1 ? b1 : b2);
      outS[(size_t)l * 1536 + i] = src[(size_t)l * 512 + off];
    }
  } else {
    for (int i = threadIdx.x; i < 1024; i += 256) {
      const float* src = (i >> 9) == 0 ? c0 : c1;
      outKV[(size_t)l * 1024 + i] = src[(size_t)l * 512 + (i & 511)];
    }
  }
}

__global__ __launch_bounds__(256)
void cvtbf16_kernel(const float* __restrict__ in, unsigned short* __restrict__ out) {
  const int i = (blockIdx.x * 256 + threadIdx.x) * 4;
  float4 v = *(const float4*)(in + i);
  out[i + 0] = f2bf(v.x); out[i + 1] = f2bf(v.y);
  out[i + 2] = f2bf(v.z); out[i + 3] = f2bf(v.w);
}

__global__ __launch_bounds__(256)
void embed_pe_kernel(const int* __restrict__ idx, const float* __restrict__ emb,
                     float* __restrict__ x, unsigned short* __restrict__ xb) {
  const int row = blockIdx.x;
  const int t = row & (TT - 1);
  const int tok = idx[row];
  const float cdiv = -0.017988946009466842f;  // -ln(10000)/512
#pragma unroll
  for (int e0 = 0; e0 < 2; ++e0) {
    const int e = threadIdx.x + e0 * 256;
    const float div = __expf((float)(e & ~1) * cdiv);
    const float ang = (float)t * div;
    const float pe = (e & 1) ? cosf(ang) : sinf(ang);
    const float v = emb[(size_t)tok * HD + e] + pe;
    x[(size_t)row * HD + e] = v;
    xb[(size_t)row * HD + e] = f2bf(v);
  }
}

// ---------------------------------------------------------------------------
// bf16 MFMA GEMM body (R8-proven): 64x64 tile, 4 waves, reg-staged LDS,
// XOR swizzle, 2-phase per 128-K. ADDRES fuses f32 residual add.
__device__ __forceinline__ void gemm_compute(const char* As, const char* Bs,
                                             int wm, int wn, int lane,
                                             f32x4 (&acc)[2][2]) {
  const int rsw = (lane & 7) << 4;
  const int csel = (lane >> 4) * 16;
  short8v af[2][2], bfr[2][2];
#pragma unroll
  for (int m = 0; m < 2; ++m)
#pragma unroll
    for (int kk = 0; kk < 2; ++kk) {
      const int row = wm * 32 + m * 16 + (lane & 15);
      af[m][kk] = *(const short8v*)(As + row * 128 + ((kk * 64 + csel) ^ rsw));
    }
#pragma unroll
  for (int n = 0; n < 2; ++n)
#pragma unroll
    for (int kk = 0; kk < 2; ++kk) {
      const int row = wn * 32 + n * 16 + (lane & 15);
      bfr[n][kk] = *(const short8v*)(Bs + row * 128 + ((kk * 64 + csel) ^ rsw));
    }
#pragma unroll
  for (int m = 0; m < 2; ++m)
#pragma unroll
    for (int n = 0; n < 2; ++n) {
      acc[m][n] = __builtin_amdgcn_mfma_f32_16x16x32_bf16(af[m][0], bfr[n][0], acc[m][n], 0, 0, 0);
      acc[m][n] = __builtin_amdgcn_mfma_f32_16x16x32_bf16(af[m][1], bfr[n][1], acc[m][n], 0, 0, 0);
    }
}

template<int OUT_BF16, int RELU, int ADDRES>
__device__ __forceinline__
void mgemm_body(const bf16* __restrict__ A, const bf16* __restrict__ Bt,
                const float* __restrict__ bias, const float* __restrict__ res,
                float* __restrict__ Cf, unsigned short* __restrict__ Cb,
                int N, int K, int m0, int n0, char* As, char* Bs) {
  const int tid = threadIdx.x;
  const int w = tid >> 6, lane = tid & 63;
  const int wm = w >> 1, wn = w & 1;

  const int sr = w * 16 + (lane >> 3);
  const int scol = (lane & 7) * 16;
  const int swc = scol ^ ((sr & 7) << 4);
  const bf16* ga0 = A + (size_t)(m0 + sr) * K + (scol >> 1);
  const bf16* ga1 = A + (size_t)(m0 + sr + 8) * K + (scol >> 1);
  const bf16* gb0 = Bt + (size_t)(n0 + sr) * K + (scol >> 1);
  const bf16* gb1 = Bt + (size_t)(n0 + sr + 8) * K + (scol >> 1);
  char* la0 = As + sr * 128 + swc;
  char* la1 = As + (sr + 8) * 128 + swc;
  char* lb0 = Bs + sr * 128 + swc;
  char* lb1 = Bs + (sr + 8) * 128 + swc;

  f32x4 acc[2][2] = {};

  short8v ra0 = *(const short8v*)ga0, ra1 = *(const short8v*)ga1;
  short8v rb0 = *(const short8v*)gb0, rb1 = *(const short8v*)gb1;
  short8v sa0, sa1, sb0, sb1;

  for (int k0 = 0; k0 < K; k0 += 128) {
    __syncthreads();
    *(short8v*)la0 = ra0; *(short8v*)la1 = ra1;
    *(short8v*)lb0 = rb0; *(short8v*)lb1 = rb1;
    __syncthreads();
    sa0 = *(const short8v*)(ga0 + k0 + 64); sa1 = *(const short8v*)(ga1 + k0 + 64);
    sb0 = *(const short8v*)(gb0 + k0 + 64); sb1 = *(const short8v*)(gb1 + k0 + 64);
    gemm_compute(As, Bs, wm, wn, lane, acc);
    __syncthreads();
    *(short8v*)la0 = sa0; *(short8v*)la1 = sa1;
    *(short8v*)lb0 = sb0; *(short8v*)lb1 = sb1;
    __syncthreads();
    if (k0 + 128 < K) {
      ra0 = *(const short8v*)(ga0 + k0 + 128); ra1 = *(const short8v*)(ga1 + k0 + 128);
      rb0 = *(const short8v*)(gb0 + k0 + 128); rb1 = *(const short8v*)(gb1 + k0 + 128);
    }
    gemm_compute(As, Bs, wm, wn, lane, acc);
  }

  const int crow = (lane >> 4) * 4;
  const int ccol = lane & 15;
#pragma unroll
  for (int m = 0; m < 2; ++m)
#pragma unroll
    for (int n = 0; n < 2; ++n) {
      const int gr = m0 + wm * 32 + m * 16 + crow;
      const int gc = n0 + wn * 32 + n * 16 + ccol;
      const float bs = bias[gc];
#pragma unroll
      for (int r = 0; r < 4; ++r) {
        float v = acc[m][n][r] + bs;
        if (RELU) v = fmaxf(v, 0.f);
        if (ADDRES) v += res[(size_t)(gr + r) * N + gc];
        if (OUT_BF16) Cb[(size_t)(gr + r) * N + gc] = f2bf(v);
        else          Cf[(size_t)(gr + r) * N + gc] = v;
      }
    }
}

template<int OUT_BF16, int RELU, int ADDRES>
__global__ __launch_bounds__(256)
void mgemm_kernel(const bf16* __restrict__ A, const bf16* __restrict__ Bt,
                  const float* __restrict__ bias, const float* __restrict__ res,
                  float* __restrict__ Cf, unsigned short* __restrict__ Cb,
                  int N, int K) {
  __shared__ __attribute__((aligned(16))) char As[64 * 128];
  __shared__ __attribute__((aligned(16))) char Bs[64 * 128];
  mgemm_body<OUT_BF16, RELU, ADDRES>(A, Bt, bias, res, Cf, Cb, N, K,
                                     blockIdx.x * 64, blockIdx.y * 64, As, Bs);
}

// ---------------------------------------------------------------------------
// all-layer cross-KV precompute, 128x128 tile (4 waves, wave 64x64).
// grid (32, 48): y -> l = y/8, n-block = y%8. Reg-staged LDS, same XOR
// swizzle rules as mgemm (128B k-rows, 8-row XOR), 2 barriers per K-64 step
// but 32 MFMA/wave/step (4x better barrier amortization than 64x64 tile).
__global__ __launch_bounds__(256)
void mgemm_eakv_kernel(const bf16* __restrict__ A, const bf16* __restrict__ BtBase,
                       const float* __restrict__ biasBase, unsigned short* __restrict__ CBase) {
  __shared__ __attribute__((aligned(16))) char As[128 * 128];
  __shared__ __attribute__((aligned(16))) char Bs[128 * 128];
  const int l = blockIdx.y >> 3, ny = blockIdx.y & 7;
  const bf16* Bt = BtBase + (size_t)l * 2 * SQC;
  const float* bias = biasBase + (size_t)l * 1024;
  unsigned short* C = CBase + (size_t)l * MROWS * 1024;
  const int m0 = blockIdx.x * 128, n0 = ny * 128;
  const int tid = threadIdx.x, w = tid >> 6, lane = tid & 63;
  const int wm = w >> 1, wn = w & 1;
  const int c8 = tid & 7, rg0 = tid >> 3;   // chunk 0..7, row-group 0..31
  const int K = 512;

  const bf16* gA[4]; const bf16* gB[4];
  char* lA[4]; char* lB[4];
#pragma unroll
  for (int j = 0; j < 4; ++j) {
    const int r = rg0 + 32 * j;
    gA[j] = A  + (size_t)(m0 + r) * K + c8 * 8;
    gB[j] = Bt + (size_t)(n0 + r) * K + c8 * 8;
    const int swz = (c8 * 16) ^ ((r & 7) << 4);
    lA[j] = As + r * 128 + swz;
    lB[j] = Bs + r * 128 + swz;
  }

  f32x4 acc[4][4] = {};
  short8v rA[4], rB[4];
#pragma unroll
  for (int j = 0; j < 4; ++j) { rA[j] = *(const short8v*)gA[j]; rB[j] = *(const short8v*)gB[j]; }

  const int l4 = lane & 15, g = lane >> 4;
  for (int t = 0; t < 8; ++t) {
    __syncthreads();   // prior compute done
#pragma unroll
    for (int j = 0; j < 4; ++j) { *(short8v*)lA[j] = rA[j]; *(short8v*)lB[j] = rB[j]; }
    __syncthreads();   // tile ready
    if (t + 1 < 8) {
#pragma unroll
      for (int j = 0; j < 4; ++j) {
        rA[j] = *(const short8v*)(gA[j] + (t + 1) * 64);
        rB[j] = *(const short8v*)(gB[j] + (t + 1) * 64);
      }
    }
#pragma unroll
    for (int kk = 0; kk < 2; ++kk) {
      short8v af[4], bv[4];
#pragma unroll
      for (int fm = 0; fm < 4; ++fm) {
        const int row = wm * 64 + fm * 16 + l4;
        af[fm] = *(const short8v*)(As + row * 128 + ((kk * 64 + g * 16) ^ ((row & 7) << 4)));
      }
#pragma unroll
      for (int fn = 0; fn < 4; ++fn) {
        const int row = wn * 64 + fn * 16 + l4;
        bv[fn] = *(const short8v*)(Bs + row * 128 + ((kk * 64 + g * 16) ^ ((row & 7) << 4)));
      }
#pragma unroll
      for (int fm = 0; fm < 4; ++fm)
#pragma unroll
        for (int fn = 0; fn < 4; ++fn)
          acc[fm][fn] = __builtin_amdgcn_mfma_f32_16x16x32_bf16(af[fm], bv[fn], acc[fm][fn], 0, 0, 0);
    }
  }

  const int crow = (lane >> 4) * 4, ccol = l4;
#pragma unroll
  for (int fm = 0; fm < 4; ++fm)
#pragma unroll
    for (int fn = 0; fn < 4; ++fn) {
      const int gr = m0 + wm * 64 + fm * 16 + crow;
      const int gc = n0 + wn * 64 + fn * 16 + ccol;
      const float bs = bias[gc];
#pragma unroll
      for (int r = 0; r < 4; ++r)
        C[(size_t)(gr + r) * 1024 + gc] = f2bf(acc[fm][fn][r] + bs);
    }
}

// ---------------------------------------------------------------------------
// MFMA flash attention v5 (R8-proven): per-wave strip assignment for causal
// balance; register prefetch of next K/V/mask tile; additive pad-mask bias;
// diagonal-only causal compare; setprio around MFMA clusters.
template<int CAUSAL>
__global__ __launch_bounds__(512)
void mattn_kernel(const unsigned short* __restrict__ q, const unsigned short* __restrict__ kgl,
                  const unsigned short* __restrict__ vgl, unsigned short* __restrict__ ctx,
                  const int* __restrict__ idx, const unsigned char* __restrict__ emask,
                  int qstride, int kvstride) {
  __shared__ __attribute__((aligned(16))) unsigned short kt[64 * 64];    // [key][d] swz
  __shared__ __attribute__((aligned(16))) unsigned short vt[64 * 64];    // [d][key] swz
  __shared__ __attribute__((aligned(16))) unsigned short pl[8][16 * 64]; // per-wave P swz
  __shared__ float km[64];                                               // pad-mask bias

  const int bh = blockIdx.x;
  const int b = bh >> 3, h = bh & 7;
  const int tid = threadIdx.x, w = tid >> 6, lane = tid & 63;
  const int l4 = lane & 15, g = lane >> 4;

  int qb_w;
  if (CAUSAL) {
    const int strip = (w < 4) ? blockIdx.y : 7 - blockIdx.y;
    qb_w = strip * 64 + (w & 3) * 16;
  } else {
    qb_w = blockIdx.y * 128 + w * 16;
  }
  const int kvEnd = CAUSAL ? (8 - blockIdx.y) * 64 : TT;

  const unsigned short* qp = q + (size_t)(b * TT + qb_w + l4) * qstride + h * DK + g * 8;
  short8v aq0 = *(const short8v*)qp;
  short8v aq1 = *(const short8v*)(qp + 32);

  const int sr_k = tid >> 3, sc8 = tid & 7;
  const unsigned short* kbp = kgl + (size_t)(b * TT + sr_k) * kvstride + h * DK + sc8 * 8;
  const int k2 = (tid & 31) * 2, d4 = (tid >> 5) * 4;
  const unsigned short* vbp0 = vgl + (size_t)(b * TT + k2) * kvstride + h * DK + d4;
  const unsigned short* vbp1 = vbp0 + kvstride;

  short8v rk = *(const short8v*)kbp;
  short4v rv0 = *(const short4v*)vbp0;
  short4v rv1 = *(const short4v*)vbp1;
  float mreg = 0.f;
  if (tid < 64) {
    const int kp = b * TT + tid;
    mreg = (CAUSAL ? (idx[kp] == 0) : (emask[kp] != 0)) ? -1e9f : 0.f;
  }

  float m_r[4], l_r[4];
  f32x4 acc_o[4];
#pragma unroll
  for (int r = 0; r < 4; ++r) { m_r[r] = -1e30f; l_r[r] = 0.f; }
#pragma unroll
  for (int f = 0; f < 4; ++f) acc_o[f] = (f32x4){0.f, 0.f, 0.f, 0.f};

  for (int kt0 = 0; kt0 < kvEnd; kt0 += 64) {
    __syncthreads();   // previous tile fully consumed
    if (tid < 64) km[tid] = mreg;
    *(short8v*)((char*)kt + sr_k * 128 + ((sc8 * 16) ^ ((sr_k & 7) << 4))) = rk;
#pragma unroll
    for (int j = 0; j < 4; ++j) {
      const int d = d4 + j;
      const unsigned pk = ((unsigned)(unsigned short)rv0[j]) | (((unsigned)(unsigned short)rv1[j]) << 16);
      *(unsigned*)((char*)vt + d * 128 + ((k2 * 2) ^ ((d & 7) << 4))) = pk;
    }
    __syncthreads();

    if (kt0 + 64 < kvEnd) {
      const size_t off = (size_t)(kt0 + 64) * kvstride;
      rk = *(const short8v*)(kbp + off);
      rv0 = *(const short4v*)(vbp0 + off);
      rv1 = *(const short4v*)(vbp1 + off);
      if (tid < 64) {
        const int kp = b * TT + kt0 + 64 + tid;
        mreg = (CAUSAL ? (idx[kp] == 0) : (emask[kp] != 0)) ? -1e9f : 0.f;
      }
    }

    if (!(CAUSAL && kt0 > qb_w + 15)) {
      const bool diag = CAUSAL && (kt0 + 64 > qb_w);

      f32x4 s4[4];
      __builtin_amdgcn_s_setprio(1);
#pragma unroll
      for (int f = 0; f < 4; ++f) {
        const int krow = f * 16 + l4;
        const int sw = (krow & 7) << 4;
        short8v bk0 = *(const short8v*)((const char*)kt + krow * 128 + ((g * 16) ^ sw));
        short8v bk1 = *(const short8v*)((const char*)kt + krow * 128 + ((64 + g * 16) ^ sw));
        f32x4 a = {};
        a = __builtin_amdgcn_mfma_f32_16x16x32_bf16(aq0, bk0, a, 0, 0, 0);
        a = __builtin_amdgcn_mfma_f32_16x16x32_bf16(aq1, bk1, a, 0, 0, 0);
        s4[f] = a;
      }
      __builtin_amdgcn_s_setprio(0);

      float kmb[4];
#pragma unroll
      for (int f = 0; f < 4; ++f) kmb[f] = km[f * 16 + l4];

      float sc_r[4];
#pragma unroll
      for (int r = 0; r < 4; ++r) {
        const int qpos = qb_w + g * 4 + r;
        float sf[4];
#pragma unroll
        for (int f = 0; f < 4; ++f) sf[f] = fmaf(s4[f][r], 0.125f, kmb[f]);
        if (diag) {
#pragma unroll
          for (int f = 0; f < 4; ++f) {
            const int kpos = kt0 + f * 16 + l4;
            sf[f] = (kpos > qpos) ? -1e9f : sf[f];
          }
        }
        float mx = fmaxf(fmaxf(sf[0], sf[1]), fmaxf(sf[2], sf[3]));
#pragma unroll
        for (int off = 8; off; off >>= 1) mx = fmaxf(mx, __shfl_xor(mx, off));
        const float mn = fmaxf(m_r[r], mx);
        const float sc = __expf(m_r[r] - mn);
        m_r[r] = mn;
        sc_r[r] = sc;
        float ps = 0.f;
        const int prow = g * 4 + r;
        const int psw = (prow & 7) << 4;
#pragma unroll
        for (int f = 0; f < 4; ++f) {
          const float p = __expf(sf[f] - mn);
          ps += p;
          *(unsigned short*)((char*)pl[w] + prow * 128 + ((f * 32 + l4 * 2) ^ psw)) = f2bf(p);
        }
#pragma unroll
        for (int off = 8; off; off >>= 1) ps += __shfl_xor(ps, off);
        l_r[r] = l_r[r] * sc + ps;
      }

#pragma unroll
      for (int f = 0; f < 4; ++f)
#pragma unroll
        for (int r = 0; r < 4; ++r) acc_o[f][r] *= sc_r[r];

      const int asw = (l4 & 7) << 4;
      short8v pa0 = *(const short8v*)((const char*)pl[w] + l4 * 128 + ((g * 16) ^ asw));
      short8v pa1 = *(const short8v*)((const char*)pl[w] + l4 * 128 + ((g * 16 + 64) ^ asw));
      __builtin_amdgcn_s_setprio(1);
#pragma unroll
      for (int f = 0; f < 4; ++f) {
        const int drow = f * 16 + l4;
        const int sw = (drow & 7) << 4;
        short8v vb0 = *(const short8v*)((const char*)vt + drow * 128 + ((g * 16) ^ sw));
        short8v vb1 = *(const short8v*)((const char*)vt + drow * 128 + ((g * 16 + 64) ^ sw));
        acc_o[f] = __builtin_amdgcn_mfma_f32_16x16x32_bf16(pa0, vb0, acc_o[f], 0, 0, 0);
        acc_o[f] = __builtin_amdgcn_mfma_f32_16x16x32_bf16(pa1, vb1, acc_o[f], 0, 0, 0);
      }
      __builtin_amdgcn_s_setprio(0);
    }
  }

  float rl[4];
#pragma unroll
  for (int r = 0; r < 4; ++r) rl[r] = 1.f / l_r[r];
#pragma unroll
  for (int f = 0; f < 4; ++f)
#pragma unroll
    for (int r = 0; r < 4; ++r) {
      const int row = qb_w + g * 4 + r;
      const int col = h * DK + f * 16 + l4;
      ctx[(size_t)(b * TT + row) * HD + col] = f2bf(acc_o[f][r] * rl[r]);
    }
}

// ---------------------------------------------------------------------------
// LayerNorm, wave-per-row (4 rows/block, no LDS, no barriers).
// v bf16 (residual already folded in by GEMM epilogue); writes f32 + bf16.
__global__ __launch_bounds__(256)
void ln2_kernel(const unsigned short* __restrict__ v, float* __restrict__ out,
                unsigned short* __restrict__ outb,
                const float* __restrict__ g, const float* __restrict__ bta) {
  const int row = blockIdx.x * 4 + (threadIdx.x >> 6);
  const int lane = threadIdx.x & 63;
  const size_t ro = (size_t)row * HD + lane * 8;

  short8v u = *(const short8v*)(v + ro);
  float f[8];
#pragma unroll
  for (int j = 0; j < 8; ++j) f[j] = bf2f((unsigned short)u[j]);

  float s = 0.f;
#pragma unroll
  for (int j = 0; j < 8; ++j) s += f[j];
  s = wave_sum(s);
  const float mean = s * (1.f / HD);

  float qv = 0.f;
#pragma unroll
  for (int j = 0; j < 8; ++j) { const float d = f[j] - mean; qv += d * d; }
  qv = wave_sum(qv);
  const float rstd = rsqrtf(qv * (1.f / HD) + 1e-5f);

  const float4 g0 = *(const float4*)(g + lane * 8);
  const float4 g1 = *(const float4*)(g + lane * 8 + 4);
  const float4 b0 = *(const float4*)(bta + lane * 8);
  const float4 b1 = *(const float4*)(bta + lane * 8 + 4);
  float gg[8] = {g0.x, g0.y, g0.z, g0.w, g1.x, g1.y, g1.z, g1.w};
  float bb[8] = {b0.x, b0.y, b0.z, b0.w, b1.x, b1.y, b1.z, b1.w};

  float o[8];
  short8v ob;
#pragma unroll
  for (int j = 0; j < 8; ++j) {
    o[j] = (f[j] - mean) * rstd * gg[j] + bb[j];
    ob[j] = (short)f2bf(o[j]);
  }
  *(float4*)(out + ro) = (float4){o[0], o[1], o[2], o[3]};
  *(float4*)(out + ro + 4) = (float4){o[4], o[5], o[6], o[7]};
  *(short8v*)(outb + ro) = ob;
}

// ---------------------------------------------------------------------------
extern "C" void kernel_launch(void* const* d_in, const int* in_sizes, int n_in,
                              void* d_out, int out_size, void* d_ws, size_t ws_size,
                              hipStream_t stream) {
  const int* idx = (const int*)d_in[0];
  const float* enc = (const float*)d_in[1];
  const unsigned char* emask = (const unsigned char*)d_in[2];
  const float* emb = (const float*)d_in[4];
  const float* sa_wq = (const float*)d_in[5];
  const float* sa_bq = (const float*)d_in[6];
  const float* sa_wk = (const float*)d_in[7];
  const float* sa_bk = (const float*)d_in[8];
  const float* sa_wv = (const float*)d_in[9];
  const float* sa_bv = (const float*)d_in[10];
  const float* sa_wo = (const float*)d_in[11];
  const float* sa_bo = (const float*)d_in[12];
  const float* ln1g = (const float*)d_in[13];
  const float* ln1b = (const float*)d_in[14];
  const float* ea_wq = (const float*)d_in[15];
  const float* ea_bq = (const float*)d_in[16];
  const float* ea_wk = (const float*)d_in[17];
  const float* ea_bk = (const float*)d_in[18];
  const float* ea_wv = (const float*)d_in[19];
  const float* ea_bv = (const float*)d_in[20];
  const float* ea_wo = (const float*)d_in[21];
  const float* ea_bo = (const float*)d_in[22];
  const float* ln2g = (const float*)d_in[23];
  const float* ln2b = (const float*)d_in[24];
  const float* c1w = (const float*)d_in[25];
  const float* c1b = (const float*)d_in[26];
  const float* c2w = (const float*)d_in[27];
  const float* c2b = (const float*)d_in[28];
  const float* ln3g = (const float*)d_in[29];
  const float* ln3b = (const float*)d_in[30];

  const size_t MH = (size_t)MROWS * HD;   // 2,097,152
  const size_t SQ = (size_t)SQC;
  char* ws = (char*)d_ws;
  float*          x    = (float*)(ws + 0);                    // 8 MB
  unsigned short* xb   = (unsigned short*)(ws + (8u << 20));  // 4 MB
  unsigned short* qkvb = (unsigned short*)(ws + (12u << 20)); // 12 MB [4096][1536]
  unsigned short* qcb  = (unsigned short*)(ws + (24u << 20)); // 4 MB
  unsigned short* cxb  = (unsigned short*)(ws + (28u << 20)); // 4 MB
  unsigned short* ybb  = (unsigned short*)(ws + (32u << 20)); // 4 MB bf16 LN input
  unsigned short* encb = (unsigned short*)(ws + (36u << 20)); // 4 MB
  bf16*           wt   = (bf16*)(ws + (40u << 20));           // 37.75 MB
  float*          bcS  = (float*)(ws + (78u << 20));          // [6][1536]
  float*          bcKV = (float*)(ws + (79u << 20));          // [6][1024]
  unsigned short* kvb6 = (unsigned short*)(ws + (80u << 20)); // 48 MB [6][4096][1024]
  unsigned short* hb   = qkvb;  // FFN hidden [4096][1024] aliases qkvb

  bf16* t_saqkv = wt;             // [6][1536][512]
  bf16* t_sao   = wt + 18 * SQ;   // [6][512][512]
  bf16* t_eaq   = wt + 24 * SQ;
  bf16* t_eakv  = wt + 30 * SQ;   // [6][1024][512]
  bf16* t_eao   = wt + 42 * SQ;
  bf16* t_c1    = wt + 48 * SQ;   // [6][1024][512]
  bf16* t_c2    = wt + 60 * SQ;   // [6][512][1024]

  const dim3 blk(256);
  const dim3 blk512(512);
  const dim3 gQKV(MROWS / 64, 1536 / 64);   // 1536 blocks
  const dim3 g1024(MROWS / 64, 1024 / 64);  // 1024 blocks
  const dim3 g512(MROWS / 64, 512 / 64);    // 512 blocks
  const dim3 gEAKV(MROWS / 128, 48);        // 1536 blocks, 128x128 tile, all layers
  const dim3 gLN(MROWS / 4);                // wave-per-row LN
  const dim3 attng(NB * NHD, 4);            // both attn variants

  Srcs8 s8;
  s8.s[0] = sa_wq; s8.s[1] = sa_wk; s8.s[2] = sa_wv; s8.s[3] = sa_wo;
  s8.s[4] = ea_wq; s8.s[5] = ea_wk; s8.s[6] = ea_wv; s8.s[7] = ea_wo;
  wprep8_kernel<<<dim3(16, 16, 48), blk, 0, stream>>>(s8, wt);
  wprep_kernel<<<dim3(32, 16, NL), blk, 0, stream>>>(c1w, t_c1, HD, DFFN);
  wprep_kernel<<<dim3(16, 32, NL), blk, 0, stream>>>(c2w, t_c2, DFFN, HD);
  bcat2_kernel<<<dim3(NL, 2), blk, 0, stream>>>(sa_bq, sa_bk, sa_bv, ea_bk, ea_bv, bcS, bcKV);
  cvtbf16_kernel<<<MH / 1024, blk, 0, stream>>>(enc, encb);
  // all-layer cross K/V precompute (depends only on enc)
  mgemm_eakv_kernel<<<gEAKV, blk, 0, stream>>>((const bf16*)encb, t_eakv, bcKV, kvb6);

  embed_pe_kernel<<<MROWS, blk, 0, stream>>>(idx, emb, x, xb);

  for (int l = 0; l < NL; ++l) {
    const size_t b512 = (size_t)l * HD;
    const size_t bFF = (size_t)l * DFFN;
    float* lnout = (l == NL - 1) ? (float*)d_out : x;
    unsigned short* kvl = kvb6 + (size_t)l * MROWS * 1024;

    // ---- self attention ----
    mgemm_kernel<1, 0, 0><<<gQKV, blk, 0, stream>>>(
        (const bf16*)xb, t_saqkv + (size_t)l * 3 * SQ, bcS + (size_t)l * 1536,
        nullptr, nullptr, qkvb, 1536, HD);
    mattn_kernel<1><<<attng, blk512, 0, stream>>>(qkvb, qkvb + 512, qkvb + 1024, cxb,
                                                  idx, emask, 1536, 1536);
    mgemm_kernel<1, 0, 1><<<g512, blk, 0, stream>>>(
        (const bf16*)cxb, t_sao + (size_t)l * SQ, sa_bo + b512, x, nullptr, ybb, HD, HD);
    ln2_kernel<<<gLN, blk, 0, stream>>>(ybb, x, xb, ln1g + b512, ln1b + b512);

    // ---- cross attention ----
    mgemm_kernel<1, 0, 0><<<g512, blk, 0, stream>>>(
        (const bf16*)xb, t_eaq + (size_t)l * SQ, ea_bq + b512, nullptr, nullptr, qcb, HD, HD);
    mattn_kernel<0><<<attng, blk512, 0, stream>>>(qcb, kvl, kvl + 512, cxb,
                                                  idx, emask, 512, 1024);
    mgemm_kernel<1, 0, 1><<<g512, blk, 0, stream>>>(
        (const bf16*)cxb, t_eao + (size_t)l * SQ, ea_bo + b512, x, nullptr, ybb, HD, HD);
    ln2_kernel<<<gLN, blk, 0, stream>>>(ybb, x, xb, ln2g + b512, ln2b + b512);

    // ---- FFN ----
    mgemm_kernel<1, 1, 0><<<g1024, blk, 0, stream>>>(
        (const bf16*)xb, t_c1 + (size_t)l * 2 * SQ, c1b + bFF, nullptr, nullptr, hb, DFFN, HD);
    mgemm_kernel<1, 0, 1><<<g512, blk, 0, stream>>>(
        (const bf16*)hb, t_c2 + (size_t)l * 2 * SQ, c2b + b512, x, nullptr, ybb, HD, DFFN);
    ln2_kernel<<<gLN, blk, 0, stream>>>(ybb, lnout, xb, ln3g + b512, ln3b + b512);
  }
}

// Round 13
// 795.724 us; speedup vs baseline: 1.0668x; 1.0048x over previous
//
#include <hip/hip_runtime.h>
#include <hip/hip_bf16.h>
#include <math.h>

#define NL   6
#define HD   512
#define NHD  8
#define DK   64
#define DFFN 1024
#define NB   8
#define TT   512
#define MROWS (NB*TT)   // 4096
#define SQC  262144     // 512*512

typedef __hip_bfloat16 bf16;
typedef __attribute__((ext_vector_type(8))) short short8v;
typedef __attribute__((ext_vector_type(4))) short short4v;
typedef __attribute__((ext_vector_type(4))) float f32x4;

__device__ __forceinline__ float wave_sum(float v) {
#pragma unroll
  for (int off = 32; off; off >>= 1) v += __shfl_xor(v, off);
  return v;
}
__device__ __forceinline__ unsigned short f2bf(float x) {
  __hip_bfloat16 h = __float2bfloat16(x);
  return *reinterpret_cast<unsigned short*>(&h);
}
__device__ __forceinline__ float bf2f(unsigned short u) {
  return __uint_as_float(((unsigned)u) << 16);
}

// ---------------------------------------------------------------------------
// Combined weight prep for the eight 512x512 slabs. grid (16,16,48).
struct Srcs8 { const float* s[8]; };
__global__ __launch_bounds__(256)
void wprep8_kernel(Srcs8 srcs, bf16* __restrict__ wt) {
  const int z = blockIdx.z;
  const int which = z & 7, l = z >> 3;
  const long long baseT[8] = {0, 0, 0, 18LL*SQC, 24LL*SQC, 30LL*SQC, 30LL*SQC, 42LL*SQC};
  const long long lstrT[8] = {3LL*SQC, 3LL*SQC, 3LL*SQC, SQC, SQC, 2LL*SQC, 2LL*SQC, SQC};
  const int rowOffT[8] = {0, 512, 1024, 0, 0, 0, 512, 0};

  __shared__ float t[32][33];
  const float* W = srcs.s[which] + (size_t)l * SQC;
  bf16* dst = wt + baseT[which] + (size_t)l * lstrT[which] + (size_t)rowOffT[which] * HD;
  const int n0 = blockIdx.x * 32, k0 = blockIdx.y * 32;
  const int tx = threadIdx.x & 31, ty = threadIdx.x >> 5;
#pragma unroll
  for (int j = 0; j < 4; ++j)
    t[ty + j * 8][tx] = W[(size_t)(k0 + ty + j * 8) * HD + n0 + tx];
  __syncthreads();
#pragma unroll
  for (int j = 0; j < 4; ++j)
    dst[(size_t)(n0 + ty + j * 8) * HD + k0 + tx] = __float2bfloat16(t[tx][ty + j * 8]);
}

// generic transpose prep for c1 (512x1024) and c2 (1024x512)
__global__ __launch_bounds__(256)
void wprep_kernel(const float* __restrict__ W, bf16* __restrict__ Wt, int Kd, int Nd) {
  __shared__ float t[32][33];
  const size_t src = (size_t)blockIdx.z * Kd * Nd;
  const int n0 = blockIdx.x * 32, k0 = blockIdx.y * 32;
  const int tx = threadIdx.x & 31, ty = threadIdx.x >> 5;
#pragma unroll
  for (int j = 0; j < 4; ++j)
    t[ty + j * 8][tx] = W[src + (size_t)(k0 + ty + j * 8) * Nd + n0 + tx];
  __syncthreads();
#pragma unroll
  for (int j = 0; j < 4; ++j)
    Wt[src + (size_t)(n0 + ty + j * 8) * Kd + k0 + tx] = __float2bfloat16(t[tx][ty + j * 8]);
}

// merged bias concats
__global__ __launch_bounds__(256)
void bcat2_kernel(const float* __restrict__ b0, const float* __restrict__ b1,
                  const float* __restrict__ b2, const float* __restrict__ c0,
                  const float* __restrict__ c1, float* __restrict__ outS,
                  float* __restrict__ outKV) {
  const int l = blockIdx.x;
  if (blockIdx.y == 0) {
    for (int i = threadIdx.x; i < 1536; i += 256) {
      const int seg = i >> 9, off = i & 511;
      const float* src = seg == 0 ? b0 : (seg == 1 ? b1 : b2);
      outS[(size_t)l * 1536 + i] = src[(size_t)l * 512 + off];
    }
  } else {
    for (int i = threadIdx.x; i < 1024; i += 256) {
      const float* src = (i >> 9) == 0 ? c0 : c1;
      outKV[(size_t)l * 1024 + i] = src[(size_t)l * 512 + (i & 511)];
    }
  }
}

__global__ __launch_bounds__(256)
void cvtbf16_kernel(const float* __restrict__ in, unsigned short* __restrict__ out) {
  const int i = (blockIdx.x * 256 + threadIdx.x) * 4;
  float4 v = *(const float4*)(in + i);
  out[i + 0] = f2bf(v.x); out[i + 1] = f2bf(v.y);
  out[i + 2] = f2bf(v.z); out[i + 3] = f2bf(v.w);
}

__global__ __launch_bounds__(256)
void embed_pe_kernel(const int* __restrict__ idx, const float* __restrict__ emb,
                     float* __restrict__ x, unsigned short* __restrict__ xb) {
  const int row = blockIdx.x;
  const int t = row & (TT - 1);
  const int tok = idx[row];
  const float cdiv = -0.017988946009466842f;  // -ln(10000)/512
#pragma unroll
  for (int e0 = 0; e0 < 2; ++e0) {
    const int e = threadIdx.x + e0 * 256;
    const float div = __expf((float)(e & ~1) * cdiv);
    const float ang = (float)t * div;
    const float pe = (e & 1) ? cosf(ang) : sinf(ang);
    const float v = emb[(size_t)tok * HD + e] + pe;
    x[(size_t)row * HD + e] = v;
    xb[(size_t)row * HD + e] = f2bf(v);
  }
}

// ---------------------------------------------------------------------------
// bf16 MFMA GEMM body (R8-proven): 64x64 tile, 4 waves, reg-staged LDS,
// XOR swizzle, 2-phase per 128-K. ADDRES fuses f32 residual add.
__device__ __forceinline__ void gemm_compute(const char* As, const char* Bs,
                                             int wm, int wn, int lane,
                                             f32x4 (&acc)[2][2]) {
  const int rsw = (lane & 7) << 4;
  const int csel = (lane >> 4) * 16;
  short8v af[2][2], bfr[2][2];
#pragma unroll
  for (int m = 0; m < 2; ++m)
#pragma unroll
    for (int kk = 0; kk < 2; ++kk) {
      const int row = wm * 32 + m * 16 + (lane & 15);
      af[m][kk] = *(const short8v*)(As + row * 128 + ((kk * 64 + csel) ^ rsw));
    }
#pragma unroll
  for (int n = 0; n < 2; ++n)
#pragma unroll
    for (int kk = 0; kk < 2; ++kk) {
      const int row = wn * 32 + n * 16 + (lane & 15);
      bfr[n][kk] = *(const short8v*)(Bs + row * 128 + ((kk * 64 + csel) ^ rsw));
    }
#pragma unroll
  for (int m = 0; m < 2; ++m)
#pragma unroll
    for (int n = 0; n < 2; ++n) {
      acc[m][n] = __builtin_amdgcn_mfma_f32_16x16x32_bf16(af[m][0], bfr[n][0], acc[m][n], 0, 0, 0);
      acc[m][n] = __builtin_amdgcn_mfma_f32_16x16x32_bf16(af[m][1], bfr[n][1], acc[m][n], 0, 0, 0);
    }
}

template<int OUT_BF16, int RELU, int ADDRES>
__device__ __forceinline__
void mgemm_body(const bf16* __restrict__ A, const bf16* __restrict__ Bt,
                const float* __restrict__ bias, const float* __restrict__ res,
                float* __restrict__ Cf, unsigned short* __restrict__ Cb,
                int N, int K, int m0, int n0, char* As, char* Bs) {
  const int tid = threadIdx.x;
  const int w = tid >> 6, lane = tid & 63;
  const int wm = w >> 1, wn = w & 1;

  const int sr = w * 16 + (lane >> 3);
  const int scol = (lane & 7) * 16;
  const int swc = scol ^ ((sr & 7) << 4);
  const bf16* ga0 = A + (size_t)(m0 + sr) * K + (scol >> 1);
  const bf16* ga1 = A + (size_t)(m0 + sr + 8) * K + (scol >> 1);
  const bf16* gb0 = Bt + (size_t)(n0 + sr) * K + (scol >> 1);
  const bf16* gb1 = Bt + (size_t)(n0 + sr + 8) * K + (scol >> 1);
  char* la0 = As + sr * 128 + swc;
  char* la1 = As + (sr + 8) * 128 + swc;
  char* lb0 = Bs + sr * 128 + swc;
  char* lb1 = Bs + (sr + 8) * 128 + swc;

  f32x4 acc[2][2] = {};

  short8v ra0 = *(const short8v*)ga0, ra1 = *(const short8v*)ga1;
  short8v rb0 = *(const short8v*)gb0, rb1 = *(const short8v*)gb1;
  short8v sa0, sa1, sb0, sb1;

  for (int k0 = 0; k0 < K; k0 += 128) {
    __syncthreads();
    *(short8v*)la0 = ra0; *(short8v*)la1 = ra1;
    *(short8v*)lb0 = rb0; *(short8v*)lb1 = rb1;
    __syncthreads();
    sa0 = *(const short8v*)(ga0 + k0 + 64); sa1 = *(const short8v*)(ga1 + k0 + 64);
    sb0 = *(const short8v*)(gb0 + k0 + 64); sb1 = *(const short8v*)(gb1 + k0 + 64);
    gemm_compute(As, Bs, wm, wn, lane, acc);
    __syncthreads();
    *(short8v*)la0 = sa0; *(short8v*)la1 = sa1;
    *(short8v*)lb0 = sb0; *(short8v*)lb1 = sb1;
    __syncthreads();
    if (k0 + 128 < K) {
      ra0 = *(const short8v*)(ga0 + k0 + 128); ra1 = *(const short8v*)(ga1 + k0 + 128);
      rb0 = *(const short8v*)(gb0 + k0 + 128); rb1 = *(const short8v*)(gb1 + k0 + 128);
    }
    gemm_compute(As, Bs, wm, wn, lane, acc);
  }

  const int crow = (lane >> 4) * 4;
  const int ccol = lane & 15;
#pragma unroll
  for (int m = 0; m < 2; ++m)
#pragma unroll
    for (int n = 0; n < 2; ++n) {
      const int gr = m0 + wm * 32 + m * 16 + crow;
      const int gc = n0 + wn * 32 + n * 16 + ccol;
      const float bs = bias[gc];
#pragma unroll
      for (int r = 0; r < 4; ++r) {
        float v = acc[m][n][r] + bs;
        if (RELU) v = fmaxf(v, 0.f);
        if (ADDRES) v += res[(size_t)(gr + r) * N + gc];
        if (OUT_BF16) Cb[(size_t)(gr + r) * N + gc] = f2bf(v);
        else          Cf[(size_t)(gr + r) * N + gc] = v;
      }
    }
}

template<int OUT_BF16, int RELU, int ADDRES>
__global__ __launch_bounds__(256)
void mgemm_kernel(const bf16* __restrict__ A, const bf16* __restrict__ Bt,
                  const float* __restrict__ bias, const float* __restrict__ res,
                  float* __restrict__ Cf, unsigned short* __restrict__ Cb,
                  int N, int K) {
  __shared__ __attribute__((aligned(16))) char As[64 * 128];
  __shared__ __attribute__((aligned(16))) char Bs[64 * 128];
  mgemm_body<OUT_BF16, RELU, ADDRES>(A, Bt, bias, res, Cf, Cb, N, K,
                                     blockIdx.x * 64, blockIdx.y * 64, As, Bs);
}

// ---------------------------------------------------------------------------
// all-layer cross-KV precompute, 128x128 tile (4 waves, wave 64x64).
__global__ __launch_bounds__(256)
void mgemm_eakv_kernel(const bf16* __restrict__ A, const bf16* __restrict__ BtBase,
                       const float* __restrict__ biasBase, unsigned short* __restrict__ CBase) {
  __shared__ __attribute__((aligned(16))) char As[128 * 128];
  __shared__ __attribute__((aligned(16))) char Bs[128 * 128];
  const int l = blockIdx.y >> 3, ny = blockIdx.y & 7;
  const bf16* Bt = BtBase + (size_t)l * 2 * SQC;
  const float* bias = biasBase + (size_t)l * 1024;
  unsigned short* C = CBase + (size_t)l * MROWS * 1024;
  const int m0 = blockIdx.x * 128, n0 = ny * 128;
  const int tid = threadIdx.x, w = tid >> 6, lane = tid & 63;
  const int wm = w >> 1, wn = w & 1;
  const int c8 = tid & 7, rg0 = tid >> 3;
  const int K = 512;

  const bf16* gA[4]; const bf16* gB[4];
  char* lA[4]; char* lB[4];
#pragma unroll
  for (int j = 0; j < 4; ++j) {
    const int r = rg0 + 32 * j;
    gA[j] = A  + (size_t)(m0 + r) * K + c8 * 8;
    gB[j] = Bt + (size_t)(n0 + r) * K + c8 * 8;
    const int swz = (c8 * 16) ^ ((r & 7) << 4);
    lA[j] = As + r * 128 + swz;
    lB[j] = Bs + r * 128 + swz;
  }

  f32x4 acc[4][4] = {};
  short8v rA[4], rB[4];
#pragma unroll
  for (int j = 0; j < 4; ++j) { rA[j] = *(const short8v*)gA[j]; rB[j] = *(const short8v*)gB[j]; }

  const int l4 = lane & 15, g = lane >> 4;
  for (int t = 0; t < 8; ++t) {
    __syncthreads();
#pragma unroll
    for (int j = 0; j < 4; ++j) { *(short8v*)lA[j] = rA[j]; *(short8v*)lB[j] = rB[j]; }
    __syncthreads();
    if (t + 1 < 8) {
#pragma unroll
      for (int j = 0; j < 4; ++j) {
        rA[j] = *(const short8v*)(gA[j] + (t + 1) * 64);
        rB[j] = *(const short8v*)(gB[j] + (t + 1) * 64);
      }
    }
#pragma unroll
    for (int kk = 0; kk < 2; ++kk) {
      short8v af[4], bv[4];
#pragma unroll
      for (int fm = 0; fm < 4; ++fm) {
        const int row = wm * 64 + fm * 16 + l4;
        af[fm] = *(const short8v*)(As + row * 128 + ((kk * 64 + g * 16) ^ ((row & 7) << 4)));
      }
#pragma unroll
      for (int fn = 0; fn < 4; ++fn) {
        const int row = wn * 64 + fn * 16 + l4;
        bv[fn] = *(const short8v*)(Bs + row * 128 + ((kk * 64 + g * 16) ^ ((row & 7) << 4)));
      }
#pragma unroll
      for (int fm = 0; fm < 4; ++fm)
#pragma unroll
        for (int fn = 0; fn < 4; ++fn)
          acc[fm][fn] = __builtin_amdgcn_mfma_f32_16x16x32_bf16(af[fm], bv[fn], acc[fm][fn], 0, 0, 0);
    }
  }

  const int crow = (lane >> 4) * 4, ccol = l4;
#pragma unroll
  for (int fm = 0; fm < 4; ++fm)
#pragma unroll
    for (int fn = 0; fn < 4; ++fn) {
      const int gr = m0 + wm * 64 + fm * 16 + crow;
      const int gc = n0 + wn * 64 + fn * 16 + ccol;
      const float bs = bias[gc];
#pragma unroll
      for (int r = 0; r < 4; ++r)
        C[(size_t)(gr + r) * 1024 + gc] = f2bf(acc[fm][fn][r] + bs);
    }
}

// ---------------------------------------------------------------------------
// MFMA flash attention v6: v5 + double-buffered K/V/mask LDS -> ONE barrier
// per KV tile (was 2). Grid = 256 blocks = 1 block/CU, so the extra 16KB LDS
// (49KB total) costs no occupancy. Reg prefetch of tile t+1 issues right
// after the barrier and flies under the whole QK/softmax/PV phase.
template<int CAUSAL>
__global__ __launch_bounds__(512)
void mattn_kernel(const unsigned short* __restrict__ q, const unsigned short* __restrict__ kgl,
                  const unsigned short* __restrict__ vgl, unsigned short* __restrict__ ctx,
                  const int* __restrict__ idx, const unsigned char* __restrict__ emask,
                  int qstride, int kvstride) {
  __shared__ __attribute__((aligned(16))) unsigned short kt[2][64 * 64];   // [key][d] swz
  __shared__ __attribute__((aligned(16))) unsigned short vt[2][64 * 64];   // [d][key] swz
  __shared__ __attribute__((aligned(16))) unsigned short pl[8][16 * 64];   // per-wave P swz
  __shared__ float km[2][64];                                              // pad-mask bias

  const int bh = blockIdx.x;
  const int b = bh >> 3, h = bh & 7;
  const int tid = threadIdx.x, w = tid >> 6, lane = tid & 63;
  const int l4 = lane & 15, g = lane >> 4;

  int qb_w;
  if (CAUSAL) {
    const int strip = (w < 4) ? blockIdx.y : 7 - blockIdx.y;
    qb_w = strip * 64 + (w & 3) * 16;
  } else {
    qb_w = blockIdx.y * 128 + w * 16;
  }
  const int kvEnd = CAUSAL ? (8 - blockIdx.y) * 64 : TT;

  const unsigned short* qp = q + (size_t)(b * TT + qb_w + l4) * qstride + h * DK + g * 8;
  short8v aq0 = *(const short8v*)qp;
  short8v aq1 = *(const short8v*)(qp + 32);

  const int sr_k = tid >> 3, sc8 = tid & 7;
  const unsigned short* kbp = kgl + (size_t)(b * TT + sr_k) * kvstride + h * DK + sc8 * 8;
  const int k2 = (tid & 31) * 2, d4 = (tid >> 5) * 4;
  const unsigned short* vbp0 = vgl + (size_t)(b * TT + k2) * kvstride + h * DK + d4;
  const unsigned short* vbp1 = vbp0 + kvstride;

  short8v rk = *(const short8v*)kbp;
  short4v rv0 = *(const short4v*)vbp0;
  short4v rv1 = *(const short4v*)vbp1;
  float mreg = 0.f;
  if (tid < 64) {
    const int kp = b * TT + tid;
    mreg = (CAUSAL ? (idx[kp] == 0) : (emask[kp] != 0)) ? -1e9f : 0.f;
  }

  float m_r[4], l_r[4];
  f32x4 acc_o[4];
#pragma unroll
  for (int r = 0; r < 4; ++r) { m_r[r] = -1e30f; l_r[r] = 0.f; }
#pragma unroll
  for (int f = 0; f < 4; ++f) acc_o[f] = (f32x4){0.f, 0.f, 0.f, 0.f};

  int tix = 0;
  for (int kt0 = 0; kt0 < kvEnd; kt0 += 64, ++tix) {
    const int buf = tix & 1;
    // ---- write prefetched registers into LDS buf ----
    if (tid < 64) km[buf][tid] = mreg;
    *(short8v*)((char*)kt[buf] + sr_k * 128 + ((sc8 * 16) ^ ((sr_k & 7) << 4))) = rk;
#pragma unroll
    for (int j = 0; j < 4; ++j) {
      const int d = d4 + j;
      const unsigned pk = ((unsigned)(unsigned short)rv0[j]) | (((unsigned)(unsigned short)rv1[j]) << 16);
      *(unsigned*)((char*)vt[buf] + d * 128 + ((k2 * 2) ^ ((d & 7) << 4))) = pk;
    }
    __syncthreads();   // ONE barrier: buf ready; iter t-2's reads of buf done

    // ---- prefetch next tile into regs (flies under compute) ----
    if (kt0 + 64 < kvEnd) {
      const size_t off = (size_t)(kt0 + 64) * kvstride;
      rk = *(const short8v*)(kbp + off);
      rv0 = *(const short4v*)(vbp0 + off);
      rv1 = *(const short4v*)(vbp1 + off);
      if (tid < 64) {
        const int kp = b * TT + kt0 + 64 + tid;
        mreg = (CAUSAL ? (idx[kp] == 0) : (emask[kp] != 0)) ? -1e9f : 0.f;
      }
    }

    if (!(CAUSAL && kt0 > qb_w + 15)) {
      const bool diag = CAUSAL && (kt0 + 64 > qb_w);

      f32x4 s4[4];
      __builtin_amdgcn_s_setprio(1);
#pragma unroll
      for (int f = 0; f < 4; ++f) {
        const int krow = f * 16 + l4;
        const int sw = (krow & 7) << 4;
        short8v bk0 = *(const short8v*)((const char*)kt[buf] + krow * 128 + ((g * 16) ^ sw));
        short8v bk1 = *(const short8v*)((const char*)kt[buf] + krow * 128 + ((64 + g * 16) ^ sw));
        f32x4 a = {};
        a = __builtin_amdgcn_mfma_f32_16x16x32_bf16(aq0, bk0, a, 0, 0, 0);
        a = __builtin_amdgcn_mfma_f32_16x16x32_bf16(aq1, bk1, a, 0, 0, 0);
        s4[f] = a;
      }
      __builtin_amdgcn_s_setprio(0);

      float kmb[4];
#pragma unroll
      for (int f = 0; f < 4; ++f) kmb[f] = km[buf][f * 16 + l4];

      float sc_r[4];
#pragma unroll
      for (int r = 0; r < 4; ++r) {
        const int qpos = qb_w + g * 4 + r;
        float sf[4];
#pragma unroll
        for (int f = 0; f < 4; ++f) sf[f] = fmaf(s4[f][r], 0.125f, kmb[f]);
        if (diag) {
#pragma unroll
          for (int f = 0; f < 4; ++f) {
            const int kpos = kt0 + f * 16 + l4;
            sf[f] = (kpos > qpos) ? -1e9f : sf[f];
          }
        }
        float mx = fmaxf(fmaxf(sf[0], sf[1]), fmaxf(sf[2], sf[3]));
#pragma unroll
        for (int off = 8; off; off >>= 1) mx = fmaxf(mx, __shfl_xor(mx, off));
        const float mn = fmaxf(m_r[r], mx);
        const float sc = __expf(m_r[r] - mn);
        m_r[r] = mn;
        sc_r[r] = sc;
        float ps = 0.f;
        const int prow = g * 4 + r;
        const int psw = (prow & 7) << 4;
#pragma unroll
        for (int f = 0; f < 4; ++f) {
          const float p = __expf(sf[f] - mn);
          ps += p;
          *(unsigned short*)((char*)pl[w] + prow * 128 + ((f * 32 + l4 * 2) ^ psw)) = f2bf(p);
        }
#pragma unroll
        for (int off = 8; off; off >>= 1) ps += __shfl_xor(ps, off);
        l_r[r] = l_r[r] * sc + ps;
      }

#pragma unroll
      for (int f = 0; f < 4; ++f)
#pragma unroll
        for (int r = 0; r < 4; ++r) acc_o[f][r] *= sc_r[r];

      const int asw = (l4 & 7) << 4;
      short8v pa0 = *(const short8v*)((const char*)pl[w] + l4 * 128 + ((g * 16) ^ asw));
      short8v pa1 = *(const short8v*)((const char*)pl[w] + l4 * 128 + ((g * 16 + 64) ^ asw));
      __builtin_amdgcn_s_setprio(1);
#pragma unroll
      for (int f = 0; f < 4; ++f) {
        const int drow = f * 16 + l4;
        const int sw = (drow & 7) << 4;
        short8v vb0 = *(const short8v*)((const char*)vt[buf] + drow * 128 + ((g * 16) ^ sw));
        short8v vb1 = *(const short8v*)((const char*)vt[buf] + drow * 128 + ((g * 16 + 64) ^ sw));
        acc_o[f] = __builtin_amdgcn_mfma_f32_16x16x32_bf16(pa0, vb0, acc_o[f], 0, 0, 0);
        acc_o[f] = __builtin_amdgcn_mfma_f32_16x16x32_bf16(pa1, vb1, acc_o[f], 0, 0, 0);
      }
      __builtin_amdgcn_s_setprio(0);
    }
  }

  float rl[4];
#pragma unroll
  for (int r = 0; r < 4; ++r) rl[r] = 1.f / l_r[r];
#pragma unroll
  for (int f = 0; f < 4; ++f)
#pragma unroll
    for (int r = 0; r < 4; ++r) {
      const int row = qb_w + g * 4 + r;
      const int col = h * DK + f * 16 + l4;
      ctx[(size_t)(b * TT + row) * HD + col] = f2bf(acc_o[f][r] * rl[r]);
    }
}

// ---------------------------------------------------------------------------
// LayerNorm, wave-per-row (4 rows/block, no LDS, no barriers).
__global__ __launch_bounds__(256)
void ln2_kernel(const unsigned short* __restrict__ v, float* __restrict__ out,
                unsigned short* __restrict__ outb,
                const float* __restrict__ g, const float* __restrict__ bta) {
  const int row = blockIdx.x * 4 + (threadIdx.x >> 6);
  const int lane = threadIdx.x & 63;
  const size_t ro = (size_t)row * HD + lane * 8;

  short8v u = *(const short8v*)(v + ro);
  float f[8];
#pragma unroll
  for (int j = 0; j < 8; ++j) f[j] = bf2f((unsigned short)u[j]);

  float s = 0.f;
#pragma unroll
  for (int j = 0; j < 8; ++j) s += f[j];
  s = wave_sum(s);
  const float mean = s * (1.f / HD);

  float qv = 0.f;
#pragma unroll
  for (int j = 0; j < 8; ++j) { const float d = f[j] - mean; qv += d * d; }
  qv = wave_sum(qv);
  const float rstd = rsqrtf(qv * (1.f / HD) + 1e-5f);

  const float4 g0 = *(const float4*)(g + lane * 8);
  const float4 g1 = *(const float4*)(g + lane * 8 + 4);
  const float4 b0 = *(const float4*)(bta + lane * 8);
  const float4 b1 = *(const float4*)(bta + lane * 8 + 4);
  float gg[8] = {g0.x, g0.y, g0.z, g0.w, g1.x, g1.y, g1.z, g1.w};
  float bb[8] = {b0.x, b0.y, b0.z, b0.w, b1.x, b1.y, b1.z, b1.w};

  float o[8];
  short8v ob;
#pragma unroll
  for (int j = 0; j < 8; ++j) {
    o[j] = (f[j] - mean) * rstd * gg[j] + bb[j];
    ob[j] = (short)f2bf(o[j]);
  }
  *(float4*)(out + ro) = (float4){o[0], o[1], o[2], o[3]};
  *(float4*)(out + ro + 4) = (float4){o[4], o[5], o[6], o[7]};
  *(short8v*)(outb + ro) = ob;
}

// ---------------------------------------------------------------------------
extern "C" void kernel_launch(void* const* d_in, const int* in_sizes, int n_in,
                              void* d_out, int out_size, void* d_ws, size_t ws_size,
                              hipStream_t stream) {
  const int* idx = (const int*)d_in[0];
  const float* enc = (const float*)d_in[1];
  const unsigned char* emask = (const unsigned char*)d_in[2];
  const float* emb = (const float*)d_in[4];
  const float* sa_wq = (const float*)d_in[5];
  const float* sa_bq = (const float*)d_in[6];
  const float* sa_wk = (const float*)d_in[7];
  const float* sa_bk = (const float*)d_in[8];
  const float* sa_wv = (const float*)d_in[9];
  const float* sa_bv = (const float*)d_in[10];
  const float* sa_wo = (const float*)d_in[11];
  const float* sa_bo = (const float*)d_in[12];
  const float* ln1g = (const float*)d_in[13];
  const float* ln1b = (const float*)d_in[14];
  const float* ea_wq = (const float*)d_in[15];
  const float* ea_bq = (const float*)d_in[16];
  const float* ea_wk = (const float*)d_in[17];
  const float* ea_bk = (const float*)d_in[18];
  const float* ea_wv = (const float*)d_in[19];
  const float* ea_bv = (const float*)d_in[20];
  const float* ea_wo = (const float*)d_in[21];
  const float* ea_bo = (const float*)d_in[22];
  const float* ln2g = (const float*)d_in[23];
  const float* ln2b = (const float*)d_in[24];
  const float* c1w = (const float*)d_in[25];
  const float* c1b = (const float*)d_in[26];
  const float* c2w = (const float*)d_in[27];
  const float* c2b = (const float*)d_in[28];
  const float* ln3g = (const float*)d_in[29];
  const float* ln3b = (const float*)d_in[30];

  const size_t MH = (size_t)MROWS * HD;   // 2,097,152
  const size_t SQ = (size_t)SQC;
  char* ws = (char*)d_ws;
  float*          x    = (float*)(ws + 0);                    // 8 MB
  unsigned short* xb   = (unsigned short*)(ws + (8u << 20));  // 4 MB
  unsigned short* qkvb = (unsigned short*)(ws + (12u << 20)); // 12 MB [4096][1536]
  unsigned short* qcb  = (unsigned short*)(ws + (24u << 20)); // 4 MB
  unsigned short* cxb  = (unsigned short*)(ws + (28u << 20)); // 4 MB
  unsigned short* ybb  = (unsigned short*)(ws + (32u << 20)); // 4 MB bf16 LN input
  unsigned short* encb = (unsigned short*)(ws + (36u << 20)); // 4 MB
  bf16*           wt   = (bf16*)(ws + (40u << 20));           // 37.75 MB
  float*          bcS  = (float*)(ws + (78u << 20));          // [6][1536]
  float*          bcKV = (float*)(ws + (79u << 20));          // [6][1024]
  unsigned short* kvb6 = (unsigned short*)(ws + (80u << 20)); // 48 MB [6][4096][1024]
  unsigned short* hb   = qkvb;  // FFN hidden [4096][1024] aliases qkvb

  bf16* t_saqkv = wt;             // [6][1536][512]
  bf16* t_sao   = wt + 18 * SQ;   // [6][512][512]
  bf16* t_eaq   = wt + 24 * SQ;
  bf16* t_eakv  = wt + 30 * SQ;   // [6][1024][512]
  bf16* t_eao   = wt + 42 * SQ;
  bf16* t_c1    = wt + 48 * SQ;   // [6][1024][512]
  bf16* t_c2    = wt + 60 * SQ;   // [6][512][1024]

  const dim3 blk(256);
  const dim3 blk512(512);
  const dim3 gQKV(MROWS / 64, 1536 / 64);   // 1536 blocks
  const dim3 g1024(MROWS / 64, 1024 / 64);  // 1024 blocks
  const dim3 g512(MROWS / 64, 512 / 64);    // 512 blocks
  const dim3 gEAKV(MROWS / 128, 48);        // 1536 blocks, 128x128 tile, all layers
  const dim3 gLN(MROWS / 4);                // wave-per-row LN
  const dim3 attng(NB * NHD, 4);            // both attn variants

  Srcs8 s8;
  s8.s[0] = sa_wq; s8.s[1] = sa_wk; s8.s[2] = sa_wv; s8.s[3] = sa_wo;
  s8.s[4] = ea_wq; s8.s[5] = ea_wk; s8.s[6] = ea_wv; s8.s[7] = ea_wo;
  wprep8_kernel<<<dim3(16, 16, 48), blk, 0, stream>>>(s8, wt);
  wprep_kernel<<<dim3(32, 16, NL), blk, 0, stream>>>(c1w, t_c1, HD, DFFN);
  wprep_kernel<<<dim3(16, 32, NL), blk, 0, stream>>>(c2w, t_c2, DFFN, HD);
  bcat2_kernel<<<dim3(NL, 2), blk, 0, stream>>>(sa_bq, sa_bk, sa_bv, ea_bk, ea_bv, bcS, bcKV);
  cvtbf16_kernel<<<MH / 1024, blk, 0, stream>>>(enc, encb);
  // all-layer cross K/V precompute (depends only on enc)
  mgemm_eakv_kernel<<<gEAKV, blk, 0, stream>>>((const bf16*)encb, t_eakv, bcKV, kvb6);

  embed_pe_kernel<<<MROWS, blk, 0, stream>>>(idx, emb, x, xb);

  for (int l = 0; l < NL; ++l) {
    const size_t b512 = (size_t)l * HD;
    const size_t bFF = (size_t)l * DFFN;
    float* lnout = (l == NL - 1) ? (float*)d_out : x;
    unsigned short* kvl = kvb6 + (size_t)l * MROWS * 1024;

    // ---- self attention ----
    mgemm_kernel<1, 0, 0><<<gQKV, blk, 0, stream>>>(
        (const bf16*)xb, t_saqkv + (size_t)l * 3 * SQ, bcS + (size_t)l * 1536,
        nullptr, nullptr, qkvb, 1536, HD);
    mattn_kernel<1><<<attng, blk512, 0, stream>>>(qkvb, qkvb + 512, qkvb + 1024, cxb,
                                                  idx, emask, 1536, 1536);
    mgemm_kernel<1, 0, 1><<<g512, blk, 0, stream>>>(
        (const bf16*)cxb, t_sao + (size_t)l * SQ, sa_bo + b512, x, nullptr, ybb, HD, HD);
    ln2_kernel<<<gLN, blk, 0, stream>>>(ybb, x, xb, ln1g + b512, ln1b + b512);

    // ---- cross attention ----
    mgemm_kernel<1, 0, 0><<<g512, blk, 0, stream>>>(
        (const bf16*)xb, t_eaq + (size_t)l * SQ, ea_bq + b512, nullptr, nullptr, qcb, HD, HD);
    mattn_kernel<0><<<attng, blk512, 0, stream>>>(qcb, kvl, kvl + 512, cxb,
                                                  idx, emask, 512, 1024);
    mgemm_kernel<1, 0, 1><<<g512, blk, 0, stream>>>(
        (const bf16*)cxb, t_eao + (size_t)l * SQ, ea_bo + b512, x, nullptr, ybb, HD, HD);
    ln2_kernel<<<gLN, blk, 0, stream>>>(ybb, x, xb, ln2g + b512, ln2b + b512);

    // ---- FFN ----
    mgemm_kernel<1, 1, 0><<<g1024, blk, 0, stream>>>(
        (const bf16*)xb, t_c1 + (size_t)l * 2 * SQ, c1b + bFF, nullptr, nullptr, hb, DFFN, HD);
    mgemm_kernel<1, 0, 1><<<g512, blk, 0, stream>>>(
        (const bf16*)hb, t_c2 + (size_t)l * 2 * SQ, c2b + b512, x, nullptr, ybb, HD, DFFN);
    ln2_kernel<<<gLN, blk, 0, stream>>>(ybb, lnout, xb, ln3g + b512, ln3b + b512);
  }
}